// Round 6
// baseline (234.547 us; speedup 1.0000x reference)
//
#include <hip/hip_runtime.h>
#include <hip/hip_bf16.h>
#include <hip/hip_fp16.h>

// ---------------------------------------------------------------------------
// GCN link prediction (math fp32, fp16 tables, MFMA GEMMs).
// Round 20: 6 dispatches.
//  - gemm2 fused into agg128: block = 64-node tile; phase A: 4 waves
//    aggregate 16 nodes each (round-19 branch-free MLP-4 body) -> relu'd
//    rows into padded LDS (stride 136 halves, 17KB); one barrier; phase B:
//    MFMA gemm_tile<64> with A from LDS. Eliminates gemm2 dispatch AND the
//    bufB HBM round-trip (25.6MB).
//  - decode: 8 pairs/wave (8 gathers in flight, was 4).
//   k1 prep+hist     (2048 blocks)
//   k2 scatter+base  (256 blocks)
//   k3 csr+gemm1     (782 blocks)
//   k4 agg128+gemm2  (782 blocks)
//   k5 agg64         (12500 blocks)
//   k6 decode        (6250 blocks)
// ---------------------------------------------------------------------------

typedef _Float16 half8 __attribute__((ext_vector_type(8)));
typedef _Float16 half4v __attribute__((ext_vector_type(4)));
typedef float   floatx4 __attribute__((ext_vector_type(4)));

#define NBLK 256   // blocks for edge-chunk passes (hist/scatter chunking)
#define LDSTR 136  // LDS row stride in halves (272B, 16B-aligned, ~2-way banks)

// ---------------------------------------------------------------------------

template<int M>
__device__ __forceinline__ void gemm_tile(const _Float16* __restrict__ Xh,
                                          const _Float16* __restrict__ Wt,
                                          _Float16* __restrict__ Y,
                                          int N, int tile, int t) {
  constexpr int K = 128;
  constexpr int CT = M / 16;
  const int lane = t & 63;
  const int i16 = lane & 15;
  const int quad = lane >> 4;
  const int row0 = tile * 64 + (t >> 6) * 16;
  int arow = row0 + i16;
  if (arow >= N) arow = N - 1;
  const _Float16* aptr = Xh + (size_t)arow * K + quad * 8;
  floatx4 acc[CT];
#pragma unroll
  for (int c = 0; c < CT; ++c) acc[c] = (floatx4){0.f, 0.f, 0.f, 0.f};
#pragma unroll
  for (int k0 = 0; k0 < K; k0 += 32) {
    half8 a = *(const half8*)(aptr + k0);
#pragma unroll
    for (int c = 0; c < CT; ++c) {
      half8 b = *(const half8*)(Wt + (size_t)(c * 16 + i16) * K + quad * 8 + k0);
      acc[c] = __builtin_amdgcn_mfma_f32_16x16x32_f16(a, b, acc[c], 0, 0, 0);
    }
  }
#pragma unroll
  for (int c = 0; c < CT; ++c) {
#pragma unroll
    for (int r = 0; r < 4; ++r) {
      int gr = row0 + quad * 4 + r;
      if (gr < N) Y[(size_t)gr * M + c * 16 + i16] = (_Float16)acc[c][r];
    }
  }
}

// ---------------------------------------------------------------------------
// k1: fused prep + per-chunk bucket histogram.
// ---------------------------------------------------------------------------
__global__ __launch_bounds__(256)
void prep_hist_kernel(const float* __restrict__ x, const float* __restrict__ W1,
                      const float* __restrict__ W2, _Float16* __restrict__ Xh,
                      _Float16* __restrict__ W1t, _Float16* __restrict__ W2t,
                      int n4, const int* __restrict__ col,
                      int* __restrict__ bhist, int ne, int chunk, int B) {
  int t = threadIdx.x, blk = blockIdx.x;
  if (blk < NBLK) {   // histogram part
    __shared__ int h[256];
    for (int b = t; b < B; b += 256) h[b] = 0;
    __syncthreads();
    int e0 = blk * chunk, e1 = min(ne, e0 + chunk);
    for (int i = e0 + t; i < e1; i += 256)
      atomicAdd(&h[col[i] >> 8], 1);
    __syncthreads();
    for (int b = t; b < B; b += 256) bhist[blk * B + b] = h[b];
  }
  // prep part: all blocks grid-stride
  const int gs = gridDim.x * 256;
  for (int i = blk * 256 + t; i < n4; i += gs) {
    float4 v = ((const float4*)x)[i];
    half4v h4; h4[0] = (_Float16)v.x; h4[1] = (_Float16)v.y;
    h4[2] = (_Float16)v.z; h4[3] = (_Float16)v.w;
    ((half4v*)Xh)[i] = h4;
    if (i < 128 * 128) { int k = i >> 7, n = i & 127; W1t[(size_t)n * 128 + k] = (_Float16)W1[i]; }
    if (i < 128 * 64)  { int k = i >> 6, n = i & 63;  W2t[(size_t)n * 128 + k] = (_Float16)W2[i]; }
  }
}

// ---------------------------------------------------------------------------
// k2: scatter with base computation fused.
// ---------------------------------------------------------------------------
__global__ __launch_bounds__(256)
void scatter_base_kernel(const int* __restrict__ row, const int* __restrict__ col,
                         const int* __restrict__ bhist, int2* __restrict__ tmp,
                         int* __restrict__ bs, int ne, int chunk, int B) {
  __shared__ int tot[256], my[256], start[257];
  int t = threadIdx.x, blk = blockIdx.x;
  if (t < B) {
    int s = 0, sp = 0;
    for (int b2 = 0; b2 < NBLK; ++b2) {
      int v = bhist[b2 * B + t];
      s += v;
      if (b2 < blk) sp += v;
    }
    tot[t] = s; my[t] = sp;
  }
  __syncthreads();
  if (t == 0) {
    int run = 0;
    for (int b = 0; b < B; ++b) { start[b] = run; run += tot[b]; }
    start[B] = run;
  }
  __syncthreads();
  if (blk == 0 && t <= B) bs[t] = start[t];
  if (t < B) tot[t] = start[t] + my[t];   // reuse tot[] as this block's cursors
  __syncthreads();
  int e0 = blk * chunk, e1 = min(ne, e0 + chunk);
  for (int i = e0 + t; i < e1; i += 256) {
    int c = col[i];
    int pos = atomicAdd(&tot[c >> 8], 1);
    tmp[pos] = make_int2(row[i], c);
  }
}

// ---------------------------------------------------------------------------
// k3: fused per-bucket CSR finalize + gemm1.
// ---------------------------------------------------------------------------
__global__ __launch_bounds__(256)
void csr_gemm1_kernel(const int2* __restrict__ tmp, const int* __restrict__ bs,
                      int* __restrict__ rowp, float* __restrict__ dis,
                      float* __restrict__ dinv, int* __restrict__ ep, int n, int B,
                      const _Float16* __restrict__ Xh, const _Float16* __restrict__ W1t,
                      _Float16* __restrict__ Y) {
  int t = threadIdx.x, b = blockIdx.x;
  if (b < B) {
    __shared__ int h[256], lo[256], cur[256];
    h[t] = 0;
    __syncthreads();
    int s0 = bs[b], s1 = bs[b + 1];
    for (int i = s0 + t; i < s1; i += 256)
      atomicAdd(&h[tmp[i].y & 255], 1);
    __syncthreads();
    if (t == 0) {
      int run = 0;
      for (int cb = 0; cb < 256; ++cb) { lo[cb] = run; run += h[cb]; }
    }
    __syncthreads();
    cur[t] = lo[t];
    int node = (b << 8) + t;
    if (node < n) {
      int c = h[t];
      rowp[node] = s0 + lo[t];
      float d = (float)(c + 1);   // +1 self loop
      dinv[node] = 1.0f / d;
      dis[node]  = rsqrtf(d);
      if (node == n - 1) rowp[n] = s1;   // last bucket end == E
    }
    __syncthreads();
    for (int i = s0 + t; i < s1; i += 256) {
      int2 rc = tmp[i];
      int r = atomicAdd(&cur[rc.y & 255], 1);
      ep[s0 + r] = rc.x;
    }
  }
  gemm_tile<128>(Xh, W1t, Y, n, b, t);
}

// ---------------------------------------------------------------------------
// k4: fused agg128 + relu + gemm2.
// Block = 64-node tile. Phase A: wave w aggregates nodes tile*64+w*16+i
// (i=0..15) with the round-19 branch-free MLP-4 body; relu'd fp16 row ->
// LDS (padded stride). Phase B: MFMA 64x64 tile, A from LDS, W2t from L2.
// bufB is never materialized in HBM. Caches wt[e]=dis[src] for agg64.
// ---------------------------------------------------------------------------
__global__ __launch_bounds__(256)
void agg128_gemm2_kernel(const __half* __restrict__ xw, const int* __restrict__ row_ptr,
                         const int* __restrict__ ep, const float* __restrict__ dis,
                         float* __restrict__ wt, const float* __restrict__ deg_inv,
                         const float* __restrict__ bias, const _Float16* __restrict__ W2t,
                         _Float16* __restrict__ Yc, int n) {
  __shared__ _Float16 hs[64 * LDSTR] __attribute__((aligned(16)));
  const int t = threadIdx.x;
  const int tile = blockIdx.x;
  const int wid = t >> 6;
  const int lane = t & 63;
  const int sub = lane & 15;
  const int q = lane >> 4;

  // ---- phase A: aggregate 16 nodes per wave ----
  for (int i = 0; i < 16; ++i) {
    const int node = tile * 64 + wid * 16 + i;
    if (node >= n) break;   // wave-uniform
    const int s0 = row_ptr[node], s1 = row_ptr[node + 1];
    const float disc = dis[node];
    float acc[2][8];
#pragma unroll
    for (int g = 0; g < 2; ++g)
#pragma unroll
      for (int j = 0; j < 8; ++j) acc[g][j] = 0.f;
    for (int e = s0; e < s1; e += 16) {
      int eg[4], sg[4];
#pragma unroll
      for (int g = 0; g < 4; ++g) {
        eg[g] = e + 4 * g + q;
        int cg = min(eg[g], s1 - 1);
        sg[g] = ep[cg];
      }
      float dg[4]; float4 raw[4];
#pragma unroll
      for (int g = 0; g < 4; ++g) {
        dg[g] = dis[sg[g]];
        raw[g] = ((const float4*)(xw + (size_t)sg[g] * 128))[sub];
      }
#pragma unroll
      for (int g = 0; g < 4; ++g) {
        bool ok = eg[g] < s1;
        if (sub == 0 && ok) wt[eg[g]] = dg[g];
        float wg = ok ? dg[g] * disc : 0.f;
        const __half2* hp = (const __half2*)&raw[g];
#pragma unroll
        for (int j = 0; j < 4; ++j) {
          float2 v = __half22float2(hp[j]);
          acc[g & 1][2 * j]     = fmaf(wg, v.x, acc[g & 1][2 * j]);
          acc[g & 1][2 * j + 1] = fmaf(wg, v.y, acc[g & 1][2 * j + 1]);
        }
      }
    }
#pragma unroll
    for (int j = 0; j < 8; ++j) {
      float s = acc[0][j] + acc[1][j];
      s += __shfl_xor(s, 16, 64);
      s += __shfl_xor(s, 32, 64);
      acc[0][j] = s;
    }
    if (q == 0) {
      float di = deg_inv[node];
      float4 sraw = ((const float4*)(xw + (size_t)node * 128))[sub];
      const __half2* sp = (const __half2*)&sraw;
      const float4* bp = (const float4*)(bias + 8 * sub);
      float o[8];
#pragma unroll
      for (int j = 0; j < 4; ++j) {
        float2 sv = __half22float2(sp[j]);
        o[2 * j]     = acc[0][2 * j]     + sv.x * di;
        o[2 * j + 1] = acc[0][2 * j + 1] + sv.y * di;
      }
      float4 b0 = bp[0], b1v = bp[1];
      o[0] += b0.x; o[1] += b0.y; o[2] += b0.z; o[3] += b0.w;
      o[4] += b1v.x; o[5] += b1v.y; o[6] += b1v.z; o[7] += b1v.w;
#pragma unroll
      for (int j = 0; j < 8; ++j) o[j] = fmaxf(o[j], 0.f);   // relu (conv1)
      half8 h8;
#pragma unroll
      for (int j = 0; j < 8; ++j) h8[j] = (_Float16)o[j];
      *(half8*)(hs + (size_t)(wid * 16 + i) * LDSTR + 8 * sub) = h8;
    }
  }
  __syncthreads();

  // ---- phase B: bufC tile = hs @ W2t^T (MFMA), rows gr<n written ----
  {
    constexpr int CT = 4;   // 64/16
    const int row0l = wid * 16;
    const _Float16* aptr = hs + (size_t)(row0l + sub) * LDSTR + q * 8;
    floatx4 acc[CT];
#pragma unroll
    for (int c = 0; c < CT; ++c) acc[c] = (floatx4){0.f, 0.f, 0.f, 0.f};
#pragma unroll
    for (int k0 = 0; k0 < 128; k0 += 32) {
      half8 a = *(const half8*)(aptr + k0);
#pragma unroll
      for (int c = 0; c < CT; ++c) {
        half8 b = *(const half8*)(W2t + (size_t)(c * 16 + sub) * 128 + q * 8 + k0);
        acc[c] = __builtin_amdgcn_mfma_f32_16x16x32_f16(a, b, acc[c], 0, 0, 0);
      }
    }
#pragma unroll
    for (int c = 0; c < CT; ++c) {
#pragma unroll
      for (int r = 0; r < 4; ++r) {
        int gr = tile * 64 + row0l + q * 4 + r;
        if (gr < n) Yc[(size_t)gr * 64 + c * 16 + sub] = (_Float16)acc[c][r];
      }
    }
  }
}

// ---------------------------------------------------------------------------
// k5: CH=64 aggregation, OCT scheme, 4 groups (32 edges) in flight,
// branch-free body. Weights from wt[] (cached by k4).
// ---------------------------------------------------------------------------
template<bool RELU>
__global__ __launch_bounds__(256)
void agg64h_kernel(const __half* __restrict__ xw, const int* __restrict__ row_ptr,
                   const int* __restrict__ ep, const float* __restrict__ wt,
                   const float* __restrict__ dis, const float* __restrict__ deg_inv,
                   const float* __restrict__ bias, __half* __restrict__ out, int n) {
  int wave = (blockIdx.x * 256 + threadIdx.x) >> 6;
  int lane = threadIdx.x & 63;
  if (wave >= n) return;
  const int node = wave;
  const int s0 = row_ptr[node], s1 = row_ptr[node + 1];
  const int sub = lane & 7;       // 8 lanes x 16B = 128B row (8 ch each)
  const int oct = lane >> 3;      // 8 edges per group
  const float disc = dis[node];
  float acc[2][8];
#pragma unroll
  for (int g = 0; g < 2; ++g)
#pragma unroll
    for (int j = 0; j < 8; ++j) acc[g][j] = 0.f;
  for (int e = s0; e < s1; e += 32) {
    int eg[4], sg[4]; float wv[4];
#pragma unroll
    for (int g = 0; g < 4; ++g) {
      eg[g] = e + 8 * g + oct;
      int cg = min(eg[g], s1 - 1);
      sg[g] = ep[cg];
      wv[g] = wt[cg];
    }
    float4 raw[4];
#pragma unroll
    for (int g = 0; g < 4; ++g)
      raw[g] = ((const float4*)(xw + (size_t)sg[g] * 64))[sub];
#pragma unroll
    for (int g = 0; g < 4; ++g) {
      float wg = (eg[g] < s1) ? wv[g] * disc : 0.f;
      const __half2* hp = (const __half2*)&raw[g];
#pragma unroll
      for (int j = 0; j < 4; ++j) {
        float2 v = __half22float2(hp[j]);
        acc[g & 1][2 * j]     = fmaf(wg, v.x, acc[g & 1][2 * j]);
        acc[g & 1][2 * j + 1] = fmaf(wg, v.y, acc[g & 1][2 * j + 1]);
      }
    }
  }
#pragma unroll
  for (int j = 0; j < 8; ++j) {
    float s = acc[0][j] + acc[1][j];
    s += __shfl_xor(s, 8, 64);
    s += __shfl_xor(s, 16, 64);
    s += __shfl_xor(s, 32, 64);
    acc[0][j] = s;
  }
  if (oct == 0) {
    float di = deg_inv[node];
    float4 sraw = ((const float4*)(xw + (size_t)node * 64))[sub];
    const __half2* sp = (const __half2*)&sraw;
    const float4* bp = (const float4*)(bias + 8 * sub);
    float o[8];
#pragma unroll
    for (int j = 0; j < 4; ++j) {
      float2 sv = __half22float2(sp[j]);
      o[2 * j]     = acc[0][2 * j]     + sv.x * di;
      o[2 * j + 1] = acc[0][2 * j + 1] + sv.y * di;
    }
    float4 b0 = bp[0], b1v = bp[1];
    o[0] += b0.x; o[1] += b0.y; o[2] += b0.z; o[3] += b0.w;
    o[4] += b1v.x; o[5] += b1v.y; o[6] += b1v.z; o[7] += b1v.w;
    if (RELU) {
#pragma unroll
      for (int j = 0; j < 8; ++j) o[j] = fmaxf(o[j], 0.f);
    }
    __half2 h2[4];
#pragma unroll
    for (int j = 0; j < 4; ++j)
      h2[j] = __float22half2_rn(make_float2(o[2 * j], o[2 * j + 1]));
    *(float4*)(out + (size_t)node * 64 + 8 * sub) = *(const float4*)h2;
  }
}

// ---------------------------------------------------------------------------
// k6: decode — 8 pairs per wave, gathers batched before reductions (ILP 8).
// ---------------------------------------------------------------------------
__global__ __launch_bounds__(256)
void decode_kernel(const __half* __restrict__ z, const int* __restrict__ eli,
                   float* __restrict__ out, int nl) {
  int wave = (blockIdx.x * 256 + threadIdx.x) >> 6;
  int lane = threadIdx.x & 63;
  int p0 = wave * 8;
  if (p0 >= nl) return;
  int sub = lane & 31;
  float2 v[8];
#pragma unroll
  for (int j = 0; j < 8; ++j) {
    int p = min(p0 + j, nl - 1);
    int src = eli[p];
    int dst = eli[nl + p];
    int node = (lane < 32) ? src : dst;
    v[j] = __half22float2(((const __half2*)(z + (size_t)node * 64))[sub]);
  }
#pragma unroll
  for (int j = 0; j < 8; ++j) {
    int p = p0 + j;
    float ox = __shfl_xor(v[j].x, 32, 64);
    float oy = __shfl_xor(v[j].y, 32, 64);
    float pr = v[j].x * ox + v[j].y * oy;
#pragma unroll
    for (int m = 16; m >= 1; m >>= 1) pr += __shfl_xor(pr, m, 64);
    if (lane == 0 && p < nl) out[p] = pr;
  }
}

// ---------------------------------------------------------------------------

extern "C" void kernel_launch(void* const* d_in, const int* in_sizes, int n_in,
                              void* d_out, int out_size, void* d_ws, size_t ws_size,
                              hipStream_t stream) {
  const float* x  = (const float*)d_in[0];
  const float* W1 = (const float*)d_in[1];
  const float* b1 = (const float*)d_in[2];
  const float* W2 = (const float*)d_in[3];
  const float* b2 = (const float*)d_in[4];
  const int* eidx = (const int*)d_in[5];
  const int* eli  = (const int*)d_in[6];
  const int N  = in_sizes[0] / 128;
  const int E  = in_sizes[5] / 2;
  const int NL = in_sizes[6] / 2;
  float* out = (float*)d_out;

  char* ws = (char*)d_ws;
  size_t off = 0;
  auto alloc = [&](size_t bytes) -> char* {
    char* p = ws + off;
    off = (off + bytes + 255) & ~(size_t)255;
    return p;
  };
  const int B = (N + 255) / 256;        // buckets (col>>8); needs N <= 65536
  const int chunk = (E + NBLK - 1) / NBLK;
  float*    dis   = (float*)   alloc((size_t)N * 4);
  float*    dinv  = (float*)   alloc((size_t)N * 4);
  int*      rowp  = (int*)     alloc((size_t)(N + 1) * 4);
  int*      bhist = (int*)     alloc((size_t)NBLK * B * 4);
  int*      bs    = (int*)     alloc((size_t)(B + 1) * 4);
  int2*     tmp   = (int2*)    alloc((size_t)E * 8);
  int*      ep    = (int*)     alloc((size_t)E * 4);
  float*    wt    = (float*)   alloc((size_t)E * 4);
  _Float16* Xh    = (_Float16*)alloc((size_t)N * 128 * 2);
  _Float16* W1t   = (_Float16*)alloc((size_t)128 * 128 * 2);
  _Float16* W2t   = (_Float16*)alloc((size_t)64 * 128 * 2);
  __half*   bufA  = (__half*)  alloc((size_t)N * 128 * 2);
  __half*   bufC  = (__half*)  alloc((size_t)N * 64 * 2);
  __half*   z     = (__half*)  alloc((size_t)N * 64 * 2);
  (void)ws_size; (void)n_in; (void)out_size;

  const int* row = eidx;      // edge_index[0]
  const int* col = eidx + E;  // edge_index[1]
  const int n4 = N * 32;      // N*128/4 float4 groups
  const int TG = (N + 63) / 64;  // 64-row tiles (782) >= B (196)

  // k1: prep + hist fused
  prep_hist_kernel<<<2048, 256, 0, stream>>>(x, W1, W2, Xh, W1t, W2t, n4,
                                             col, bhist, E, chunk, B);
  // k2: scatter with fused base computation
  scatter_base_kernel<<<NBLK, 256, 0, stream>>>(row, col, bhist, tmp, bs, E, chunk, B);
  // k3: CSR finalize + gemm1 fused (bufA = half(Xh@W1))
  csr_gemm1_kernel<<<TG, 256, 0, stream>>>(tmp, bs, rowp, dis, dinv, ep, N, B,
                                           Xh, W1t, (_Float16*)bufA);
  // k4: bufC = half(relu(agg(bufA)+dinv*bufA+b1) @ W2); caches wt[]
  agg128_gemm2_kernel<<<TG, 256, 0, stream>>>(bufA, rowp, ep, dis, wt, dinv, b1,
                                              W2t, (_Float16*)bufC, N);
  // k5: z = half(agg(bufC)+dinv*bufC+b2) using cached wt[]
  agg64h_kernel<false><<<(N + 3) / 4, 256, 0, stream>>>(bufC, rowp, ep, wt, dis,
                                                        dinv, b2, z, N);
  // k6: decode (8 pairs/wave)
  decode_kernel<<<(NL + 31) / 32, 256, 0, stream>>>(z, eli, out, NL);
}

// Round 7
// 224.562 us; speedup vs baseline: 1.0445x; 1.0445x over previous
//
#include <hip/hip_runtime.h>
#include <hip/hip_bf16.h>
#include <hip/hip_fp16.h>

// ---------------------------------------------------------------------------
// GCN link prediction (math fp32, fp16 tables, MFMA GEMMs).
// Round 21: revert round-20's agg128+gemm2 fusion (782-block tile serialized
// 16 nodes/wave -> occupancy 25%, 58.6us vs ~43 split; wave-count IS the
// resource for latency-bound gathers). Back to round-19's 7-dispatch split,
// keep decode-8, and deepen agg128 MLP 4->6 edge-groups (24 edges/iter;
// Poisson(16) degree => 2nd serial iteration drops from 46% to 2% of nodes).
//   k1 prep+hist   (2048 blocks)
//   k2 scatter+base(256 blocks)
//   k3 csr+gemm1   (782 blocks)
//   k4 agg128+relu (12500 blocks, 6 groups)
//   k5 gemm2       (782 blocks)
//   k6 agg64       (12500 blocks, 4 groups)
//   k7 decode      (6250 blocks, 8 pairs/wave)
// ---------------------------------------------------------------------------

typedef _Float16 half8 __attribute__((ext_vector_type(8)));
typedef _Float16 half4v __attribute__((ext_vector_type(4)));
typedef float   floatx4 __attribute__((ext_vector_type(4)));

#define NBLK 256  // blocks for edge-chunk passes (hist/scatter chunking)

// ---------------------------------------------------------------------------

template<int M>
__device__ __forceinline__ void gemm_tile(const _Float16* __restrict__ Xh,
                                          const _Float16* __restrict__ Wt,
                                          _Float16* __restrict__ Y,
                                          int N, int tile, int t) {
  constexpr int K = 128;
  constexpr int CT = M / 16;
  const int lane = t & 63;
  const int i16 = lane & 15;
  const int quad = lane >> 4;
  const int row0 = tile * 64 + (t >> 6) * 16;
  int arow = row0 + i16;
  if (arow >= N) arow = N - 1;
  const _Float16* aptr = Xh + (size_t)arow * K + quad * 8;
  floatx4 acc[CT];
#pragma unroll
  for (int c = 0; c < CT; ++c) acc[c] = (floatx4){0.f, 0.f, 0.f, 0.f};
#pragma unroll
  for (int k0 = 0; k0 < K; k0 += 32) {
    half8 a = *(const half8*)(aptr + k0);
#pragma unroll
    for (int c = 0; c < CT; ++c) {
      half8 b = *(const half8*)(Wt + (size_t)(c * 16 + i16) * K + quad * 8 + k0);
      acc[c] = __builtin_amdgcn_mfma_f32_16x16x32_f16(a, b, acc[c], 0, 0, 0);
    }
  }
#pragma unroll
  for (int c = 0; c < CT; ++c) {
#pragma unroll
    for (int r = 0; r < 4; ++r) {
      int gr = row0 + quad * 4 + r;
      if (gr < N) Y[(size_t)gr * M + c * 16 + i16] = (_Float16)acc[c][r];
    }
  }
}

// ---------------------------------------------------------------------------
// k1: fused prep + per-chunk bucket histogram.
// ---------------------------------------------------------------------------
__global__ __launch_bounds__(256)
void prep_hist_kernel(const float* __restrict__ x, const float* __restrict__ W1,
                      const float* __restrict__ W2, _Float16* __restrict__ Xh,
                      _Float16* __restrict__ W1t, _Float16* __restrict__ W2t,
                      int n4, const int* __restrict__ col,
                      int* __restrict__ bhist, int ne, int chunk, int B) {
  int t = threadIdx.x, blk = blockIdx.x;
  if (blk < NBLK) {   // histogram part
    __shared__ int h[256];
    for (int b = t; b < B; b += 256) h[b] = 0;
    __syncthreads();
    int e0 = blk * chunk, e1 = min(ne, e0 + chunk);
    for (int i = e0 + t; i < e1; i += 256)
      atomicAdd(&h[col[i] >> 8], 1);
    __syncthreads();
    for (int b = t; b < B; b += 256) bhist[blk * B + b] = h[b];
  }
  // prep part: all blocks grid-stride
  const int gs = gridDim.x * 256;
  for (int i = blk * 256 + t; i < n4; i += gs) {
    float4 v = ((const float4*)x)[i];
    half4v h4; h4[0] = (_Float16)v.x; h4[1] = (_Float16)v.y;
    h4[2] = (_Float16)v.z; h4[3] = (_Float16)v.w;
    ((half4v*)Xh)[i] = h4;
    if (i < 128 * 128) { int k = i >> 7, n = i & 127; W1t[(size_t)n * 128 + k] = (_Float16)W1[i]; }
    if (i < 128 * 64)  { int k = i >> 6, n = i & 63;  W2t[(size_t)n * 128 + k] = (_Float16)W2[i]; }
  }
}

// ---------------------------------------------------------------------------
// k2: scatter with base computation fused.
// ---------------------------------------------------------------------------
__global__ __launch_bounds__(256)
void scatter_base_kernel(const int* __restrict__ row, const int* __restrict__ col,
                         const int* __restrict__ bhist, int2* __restrict__ tmp,
                         int* __restrict__ bs, int ne, int chunk, int B) {
  __shared__ int tot[256], my[256], start[257];
  int t = threadIdx.x, blk = blockIdx.x;
  if (t < B) {
    int s = 0, sp = 0;
    for (int b2 = 0; b2 < NBLK; ++b2) {
      int v = bhist[b2 * B + t];
      s += v;
      if (b2 < blk) sp += v;
    }
    tot[t] = s; my[t] = sp;
  }
  __syncthreads();
  if (t == 0) {
    int run = 0;
    for (int b = 0; b < B; ++b) { start[b] = run; run += tot[b]; }
    start[B] = run;
  }
  __syncthreads();
  if (blk == 0 && t <= B) bs[t] = start[t];
  if (t < B) tot[t] = start[t] + my[t];   // reuse tot[] as this block's cursors
  __syncthreads();
  int e0 = blk * chunk, e1 = min(ne, e0 + chunk);
  for (int i = e0 + t; i < e1; i += 256) {
    int c = col[i];
    int pos = atomicAdd(&tot[c >> 8], 1);
    tmp[pos] = make_int2(row[i], c);
  }
}

// ---------------------------------------------------------------------------
// k3: fused per-bucket CSR finalize + gemm1.
// ---------------------------------------------------------------------------
__global__ __launch_bounds__(256)
void csr_gemm1_kernel(const int2* __restrict__ tmp, const int* __restrict__ bs,
                      int* __restrict__ rowp, float* __restrict__ dis,
                      float* __restrict__ dinv, int* __restrict__ ep, int n, int B,
                      const _Float16* __restrict__ Xh, const _Float16* __restrict__ W1t,
                      _Float16* __restrict__ Y) {
  int t = threadIdx.x, b = blockIdx.x;
  if (b < B) {
    __shared__ int h[256], lo[256], cur[256];
    h[t] = 0;
    __syncthreads();
    int s0 = bs[b], s1 = bs[b + 1];
    for (int i = s0 + t; i < s1; i += 256)
      atomicAdd(&h[tmp[i].y & 255], 1);
    __syncthreads();
    if (t == 0) {
      int run = 0;
      for (int cb = 0; cb < 256; ++cb) { lo[cb] = run; run += h[cb]; }
    }
    __syncthreads();
    cur[t] = lo[t];
    int node = (b << 8) + t;
    if (node < n) {
      int c = h[t];
      rowp[node] = s0 + lo[t];
      float d = (float)(c + 1);   // +1 self loop
      dinv[node] = 1.0f / d;
      dis[node]  = rsqrtf(d);
      if (node == n - 1) rowp[n] = s1;   // last bucket end == E
    }
    __syncthreads();
    for (int i = s0 + t; i < s1; i += 256) {
      int2 rc = tmp[i];
      int r = atomicAdd(&cur[rc.y & 255], 1);
      ep[s0 + r] = rc.x;
    }
  }
  gemm_tile<128>(Xh, W1t, Y, n, b, t);
}

// ---------------------------------------------------------------------------
// k4: CH=128 aggregation, quarter scheme, 6 groups (24 edges) in flight,
// branch-free body: all loads unconditional (clamped), weights masked.
// Caches wt[e] = dis[src] for the second pass.
// ---------------------------------------------------------------------------
template<bool RELU>
__global__ __launch_bounds__(256)
void agg128h_kernel(const __half* __restrict__ xw, const int* __restrict__ row_ptr,
                    const int* __restrict__ ep, const float* __restrict__ dis,
                    float* __restrict__ wt, const float* __restrict__ deg_inv,
                    const float* __restrict__ bias, __half* __restrict__ out, int n) {
  int wave = (blockIdx.x * 256 + threadIdx.x) >> 6;
  int lane = threadIdx.x & 63;
  if (wave >= n) return;
  const int node = wave;
  const int s0 = row_ptr[node], s1 = row_ptr[node + 1];
  const int sub = lane & 15;
  const int q = lane >> 4;
  const float disc = dis[node];
  float acc[2][8];
#pragma unroll
  for (int g = 0; g < 2; ++g)
#pragma unroll
    for (int j = 0; j < 8; ++j) acc[g][j] = 0.f;
  for (int e = s0; e < s1; e += 24) {
    int eg[6], sg[6];
#pragma unroll
    for (int g = 0; g < 6; ++g) {
      eg[g] = e + 4 * g + q;
      int cg = min(eg[g], s1 - 1);
      sg[g] = ep[cg];
    }
    float dg[6]; float4 raw[6];
#pragma unroll
    for (int g = 0; g < 6; ++g) {
      dg[g] = dis[sg[g]];
      raw[g] = ((const float4*)(xw + (size_t)sg[g] * 128))[sub];
    }
#pragma unroll
    for (int g = 0; g < 6; ++g) {
      bool ok = eg[g] < s1;
      if (sub == 0 && ok) wt[eg[g]] = dg[g];
      float wg = ok ? dg[g] * disc : 0.f;
      const __half2* hp = (const __half2*)&raw[g];
#pragma unroll
      for (int j = 0; j < 4; ++j) {
        float2 v = __half22float2(hp[j]);
        acc[g & 1][2 * j]     = fmaf(wg, v.x, acc[g & 1][2 * j]);
        acc[g & 1][2 * j + 1] = fmaf(wg, v.y, acc[g & 1][2 * j + 1]);
      }
    }
  }
#pragma unroll
  for (int j = 0; j < 8; ++j) {
    float s = acc[0][j] + acc[1][j];
    s += __shfl_xor(s, 16, 64);
    s += __shfl_xor(s, 32, 64);
    acc[0][j] = s;
  }
  if (q == 0) {
    float di = deg_inv[node];
    float4 sraw = ((const float4*)(xw + (size_t)node * 128))[sub];
    const __half2* sp = (const __half2*)&sraw;
    const float4* bp = (const float4*)(bias + 8 * sub);
    float o[8];
#pragma unroll
    for (int j = 0; j < 4; ++j) {
      float2 sv = __half22float2(sp[j]);
      o[2 * j]     = acc[0][2 * j]     + sv.x * di;
      o[2 * j + 1] = acc[0][2 * j + 1] + sv.y * di;
    }
    float4 b0 = bp[0], b1v = bp[1];
    o[0] += b0.x; o[1] += b0.y; o[2] += b0.z; o[3] += b0.w;
    o[4] += b1v.x; o[5] += b1v.y; o[6] += b1v.z; o[7] += b1v.w;
    if (RELU) {
#pragma unroll
      for (int j = 0; j < 8; ++j) o[j] = fmaxf(o[j], 0.f);
    }
    __half2 h2[4];
#pragma unroll
    for (int j = 0; j < 4; ++j)
      h2[j] = __float22half2_rn(make_float2(o[2 * j], o[2 * j + 1]));
    *(float4*)(out + (size_t)node * 128 + 8 * sub) = *(const float4*)h2;
  }
}

// ---------------------------------------------------------------------------
// k6: CH=64 aggregation, OCT scheme, 4 groups (32 edges) in flight,
// branch-free body. Weights from wt[] (cached by agg128).
// ---------------------------------------------------------------------------
template<bool RELU>
__global__ __launch_bounds__(256)
void agg64h_kernel(const __half* __restrict__ xw, const int* __restrict__ row_ptr,
                   const int* __restrict__ ep, const float* __restrict__ wt,
                   const float* __restrict__ dis, const float* __restrict__ deg_inv,
                   const float* __restrict__ bias, __half* __restrict__ out, int n) {
  int wave = (blockIdx.x * 256 + threadIdx.x) >> 6;
  int lane = threadIdx.x & 63;
  if (wave >= n) return;
  const int node = wave;
  const int s0 = row_ptr[node], s1 = row_ptr[node + 1];
  const int sub = lane & 7;       // 8 lanes x 16B = 128B row (8 ch each)
  const int oct = lane >> 3;      // 8 edges per group
  const float disc = dis[node];
  float acc[2][8];
#pragma unroll
  for (int g = 0; g < 2; ++g)
#pragma unroll
    for (int j = 0; j < 8; ++j) acc[g][j] = 0.f;
  for (int e = s0; e < s1; e += 32) {
    int eg[4], sg[4]; float wv[4];
#pragma unroll
    for (int g = 0; g < 4; ++g) {
      eg[g] = e + 8 * g + oct;
      int cg = min(eg[g], s1 - 1);
      sg[g] = ep[cg];
      wv[g] = wt[cg];
    }
    float4 raw[4];
#pragma unroll
    for (int g = 0; g < 4; ++g)
      raw[g] = ((const float4*)(xw + (size_t)sg[g] * 64))[sub];
#pragma unroll
    for (int g = 0; g < 4; ++g) {
      float wg = (eg[g] < s1) ? wv[g] * disc : 0.f;
      const __half2* hp = (const __half2*)&raw[g];
#pragma unroll
      for (int j = 0; j < 4; ++j) {
        float2 v = __half22float2(hp[j]);
        acc[g & 1][2 * j]     = fmaf(wg, v.x, acc[g & 1][2 * j]);
        acc[g & 1][2 * j + 1] = fmaf(wg, v.y, acc[g & 1][2 * j + 1]);
      }
    }
  }
#pragma unroll
  for (int j = 0; j < 8; ++j) {
    float s = acc[0][j] + acc[1][j];
    s += __shfl_xor(s, 8, 64);
    s += __shfl_xor(s, 16, 64);
    s += __shfl_xor(s, 32, 64);
    acc[0][j] = s;
  }
  if (oct == 0) {
    float di = deg_inv[node];
    float4 sraw = ((const float4*)(xw + (size_t)node * 64))[sub];
    const __half2* sp = (const __half2*)&sraw;
    const float4* bp = (const float4*)(bias + 8 * sub);
    float o[8];
#pragma unroll
    for (int j = 0; j < 4; ++j) {
      float2 sv = __half22float2(sp[j]);
      o[2 * j]     = acc[0][2 * j]     + sv.x * di;
      o[2 * j + 1] = acc[0][2 * j + 1] + sv.y * di;
    }
    float4 b0 = bp[0], b1v = bp[1];
    o[0] += b0.x; o[1] += b0.y; o[2] += b0.z; o[3] += b0.w;
    o[4] += b1v.x; o[5] += b1v.y; o[6] += b1v.z; o[7] += b1v.w;
    if (RELU) {
#pragma unroll
      for (int j = 0; j < 8; ++j) o[j] = fmaxf(o[j], 0.f);
    }
    __half2 h2[4];
#pragma unroll
    for (int j = 0; j < 4; ++j)
      h2[j] = __float22half2_rn(make_float2(o[2 * j], o[2 * j + 1]));
    *(float4*)(out + (size_t)node * 64 + 8 * sub) = *(const float4*)h2;
  }
}

// k5: standalone gemm2.
template<int M>
__global__ __launch_bounds__(256)
void gemm_mfma_kernel(const _Float16* __restrict__ Xh,
                      const _Float16* __restrict__ Wt,
                      _Float16* __restrict__ Y, int N) {
  gemm_tile<M>(Xh, Wt, Y, N, blockIdx.x, threadIdx.x);
}

// ---------------------------------------------------------------------------
// k7: decode — 8 pairs per wave, gathers batched before reductions (ILP 8).
// ---------------------------------------------------------------------------
__global__ __launch_bounds__(256)
void decode_kernel(const __half* __restrict__ z, const int* __restrict__ eli,
                   float* __restrict__ out, int nl) {
  int wave = (blockIdx.x * 256 + threadIdx.x) >> 6;
  int lane = threadIdx.x & 63;
  int p0 = wave * 8;
  if (p0 >= nl) return;
  int sub = lane & 31;
  float2 v[8];
#pragma unroll
  for (int j = 0; j < 8; ++j) {
    int p = min(p0 + j, nl - 1);
    int src = eli[p];
    int dst = eli[nl + p];
    int node = (lane < 32) ? src : dst;
    v[j] = __half22float2(((const __half2*)(z + (size_t)node * 64))[sub]);
  }
#pragma unroll
  for (int j = 0; j < 8; ++j) {
    int p = p0 + j;
    float ox = __shfl_xor(v[j].x, 32, 64);
    float oy = __shfl_xor(v[j].y, 32, 64);
    float pr = v[j].x * ox + v[j].y * oy;
#pragma unroll
    for (int m = 16; m >= 1; m >>= 1) pr += __shfl_xor(pr, m, 64);
    if (lane == 0 && p < nl) out[p] = pr;
  }
}

// ---------------------------------------------------------------------------

extern "C" void kernel_launch(void* const* d_in, const int* in_sizes, int n_in,
                              void* d_out, int out_size, void* d_ws, size_t ws_size,
                              hipStream_t stream) {
  const float* x  = (const float*)d_in[0];
  const float* W1 = (const float*)d_in[1];
  const float* b1 = (const float*)d_in[2];
  const float* W2 = (const float*)d_in[3];
  const float* b2 = (const float*)d_in[4];
  const int* eidx = (const int*)d_in[5];
  const int* eli  = (const int*)d_in[6];
  const int N  = in_sizes[0] / 128;
  const int E  = in_sizes[5] / 2;
  const int NL = in_sizes[6] / 2;
  float* out = (float*)d_out;

  char* ws = (char*)d_ws;
  size_t off = 0;
  auto alloc = [&](size_t bytes) -> char* {
    char* p = ws + off;
    off = (off + bytes + 255) & ~(size_t)255;
    return p;
  };
  const int B = (N + 255) / 256;        // buckets (col>>8); needs N <= 65536
  const int chunk = (E + NBLK - 1) / NBLK;
  float*    dis   = (float*)   alloc((size_t)N * 4);
  float*    dinv  = (float*)   alloc((size_t)N * 4);
  int*      rowp  = (int*)     alloc((size_t)(N + 1) * 4);
  int*      bhist = (int*)     alloc((size_t)NBLK * B * 4);
  int*      bs    = (int*)     alloc((size_t)(B + 1) * 4);
  int2*     tmp   = (int2*)    alloc((size_t)E * 8);
  int*      ep    = (int*)     alloc((size_t)E * 4);
  float*    wt    = (float*)   alloc((size_t)E * 4);
  _Float16* Xh    = (_Float16*)alloc((size_t)N * 128 * 2);
  _Float16* W1t   = (_Float16*)alloc((size_t)128 * 128 * 2);
  _Float16* W2t   = (_Float16*)alloc((size_t)64 * 128 * 2);
  __half*   bufA  = (__half*)  alloc((size_t)N * 128 * 2);
  __half*   bufB  = (__half*)  alloc((size_t)N * 128 * 2);
  __half*   bufC  = (__half*)  alloc((size_t)N * 64 * 2);
  __half*   z     = (__half*)  alloc((size_t)N * 64 * 2);
  (void)ws_size; (void)n_in; (void)out_size;

  const int* row = eidx;      // edge_index[0]
  const int* col = eidx + E;  // edge_index[1]
  const int n4 = N * 32;      // N*128/4 float4 groups
  const int TG = (N + 63) / 64;  // gemm tiles (782) >= B (196)

  // k1: prep + hist fused
  prep_hist_kernel<<<2048, 256, 0, stream>>>(x, W1, W2, Xh, W1t, W2t, n4,
                                             col, bhist, E, chunk, B);
  // k2: scatter with fused base computation
  scatter_base_kernel<<<NBLK, 256, 0, stream>>>(row, col, bhist, tmp, bs, E, chunk, B);
  // k3: CSR finalize + gemm1 fused (bufA = half(Xh@W1))
  csr_gemm1_kernel<<<TG, 256, 0, stream>>>(tmp, bs, rowp, dis, dinv, ep, N, B,
                                           Xh, W1t, (_Float16*)bufA);
  // k4: bufB = half(relu(agg(bufA)+dinv*bufA+b1)); caches wt[]
  agg128h_kernel<true><<<(N + 3) / 4, 256, 0, stream>>>(bufA, rowp, ep, dis, wt,
                                                        dinv, b1, bufB, N);
  // k5: bufC = half(bufB@W2)
  gemm_mfma_kernel<64><<<TG, 256, 0, stream>>>((const _Float16*)bufB, W2t,
                                               (_Float16*)bufC, N);
  // k6: z = half(agg(bufC)+dinv*bufC+b2) using cached wt[]
  agg64h_kernel<false><<<(N + 3) / 4, 256, 0, stream>>>(bufC, rowp, ep, wt, dis,
                                                        dinv, b2, z, N);
  // k7: decode (8 pairs/wave)
  decode_kernel<<<(NL + 31) / 32, 256, 0, stream>>>(z, eli, out, NL);
}

// Round 8
// 222.058 us; speedup vs baseline: 1.0562x; 1.0113x over previous
//
#include <hip/hip_runtime.h>
#include <hip/hip_bf16.h>
#include <hip/hip_fp16.h>

// ---------------------------------------------------------------------------
// GCN link prediction (math fp32, fp16 tables, MFMA GEMMs).
// Round 22: 7 dispatches; four independent micro-fixes:
//  1. csr_gemm1: CSR blocks (b<B) no longer run a gemm tile afterwards;
//     blocks >= B stride all tiles (<=2 each). max() instead of sum().
//  2. agg128 writes packed epw[e]={src, w} (int2); agg64 loads ONE 8B value
//     per edge instead of two 4B loads.
//  3. aggs prefetch deg_inv + self-row before the edge loop.
//  4. decode: 12 pairs/wave (24 gathers in flight).
//   k1 prep+hist   (2048 blocks)
//   k2 scatter+base(256 blocks)
//   k3 csr+gemm1   (782 blocks, decoupled roles)
//   k4 agg128+relu (12500 blocks, 6 groups)
//   k5 gemm2       (782 blocks)
//   k6 agg64       (12500 blocks, 4 groups, packed payload)
//   k7 decode      (4167 blocks, 12 pairs/wave)
// ---------------------------------------------------------------------------

typedef _Float16 half8 __attribute__((ext_vector_type(8)));
typedef _Float16 half4v __attribute__((ext_vector_type(4)));
typedef float   floatx4 __attribute__((ext_vector_type(4)));

#define NBLK 256  // blocks for edge-chunk passes (hist/scatter chunking)

// ---------------------------------------------------------------------------

template<int M>
__device__ __forceinline__ void gemm_tile(const _Float16* __restrict__ Xh,
                                          const _Float16* __restrict__ Wt,
                                          _Float16* __restrict__ Y,
                                          int N, int tile, int t) {
  constexpr int K = 128;
  constexpr int CT = M / 16;
  const int lane = t & 63;
  const int i16 = lane & 15;
  const int quad = lane >> 4;
  const int row0 = tile * 64 + (t >> 6) * 16;
  int arow = row0 + i16;
  if (arow >= N) arow = N - 1;
  const _Float16* aptr = Xh + (size_t)arow * K + quad * 8;
  floatx4 acc[CT];
#pragma unroll
  for (int c = 0; c < CT; ++c) acc[c] = (floatx4){0.f, 0.f, 0.f, 0.f};
#pragma unroll
  for (int k0 = 0; k0 < K; k0 += 32) {
    half8 a = *(const half8*)(aptr + k0);
#pragma unroll
    for (int c = 0; c < CT; ++c) {
      half8 b = *(const half8*)(Wt + (size_t)(c * 16 + i16) * K + quad * 8 + k0);
      acc[c] = __builtin_amdgcn_mfma_f32_16x16x32_f16(a, b, acc[c], 0, 0, 0);
    }
  }
#pragma unroll
  for (int c = 0; c < CT; ++c) {
#pragma unroll
    for (int r = 0; r < 4; ++r) {
      int gr = row0 + quad * 4 + r;
      if (gr < N) Y[(size_t)gr * M + c * 16 + i16] = (_Float16)acc[c][r];
    }
  }
}

// ---------------------------------------------------------------------------
// k1: fused prep + per-chunk bucket histogram.
// ---------------------------------------------------------------------------
__global__ __launch_bounds__(256)
void prep_hist_kernel(const float* __restrict__ x, const float* __restrict__ W1,
                      const float* __restrict__ W2, _Float16* __restrict__ Xh,
                      _Float16* __restrict__ W1t, _Float16* __restrict__ W2t,
                      int n4, const int* __restrict__ col,
                      int* __restrict__ bhist, int ne, int chunk, int B) {
  int t = threadIdx.x, blk = blockIdx.x;
  if (blk < NBLK) {   // histogram part
    __shared__ int h[256];
    for (int b = t; b < B; b += 256) h[b] = 0;
    __syncthreads();
    int e0 = blk * chunk, e1 = min(ne, e0 + chunk);
    for (int i = e0 + t; i < e1; i += 256)
      atomicAdd(&h[col[i] >> 8], 1);
    __syncthreads();
    for (int b = t; b < B; b += 256) bhist[blk * B + b] = h[b];
  }
  // prep part: all blocks grid-stride
  const int gs = gridDim.x * 256;
  for (int i = blk * 256 + t; i < n4; i += gs) {
    float4 v = ((const float4*)x)[i];
    half4v h4; h4[0] = (_Float16)v.x; h4[1] = (_Float16)v.y;
    h4[2] = (_Float16)v.z; h4[3] = (_Float16)v.w;
    ((half4v*)Xh)[i] = h4;
    if (i < 128 * 128) { int k = i >> 7, n = i & 127; W1t[(size_t)n * 128 + k] = (_Float16)W1[i]; }
    if (i < 128 * 64)  { int k = i >> 6, n = i & 63;  W2t[(size_t)n * 128 + k] = (_Float16)W2[i]; }
  }
}

// ---------------------------------------------------------------------------
// k2: scatter with base computation fused.
// ---------------------------------------------------------------------------
__global__ __launch_bounds__(256)
void scatter_base_kernel(const int* __restrict__ row, const int* __restrict__ col,
                         const int* __restrict__ bhist, int2* __restrict__ tmp,
                         int* __restrict__ bs, int ne, int chunk, int B) {
  __shared__ int tot[256], my[256], start[257];
  int t = threadIdx.x, blk = blockIdx.x;
  if (t < B) {
    int s = 0, sp = 0;
    for (int b2 = 0; b2 < NBLK; ++b2) {
      int v = bhist[b2 * B + t];
      s += v;
      if (b2 < blk) sp += v;
    }
    tot[t] = s; my[t] = sp;
  }
  __syncthreads();
  if (t == 0) {
    int run = 0;
    for (int b = 0; b < B; ++b) { start[b] = run; run += tot[b]; }
    start[B] = run;
  }
  __syncthreads();
  if (blk == 0 && t <= B) bs[t] = start[t];
  if (t < B) tot[t] = start[t] + my[t];   // reuse tot[] as this block's cursors
  __syncthreads();
  int e0 = blk * chunk, e1 = min(ne, e0 + chunk);
  for (int i = e0 + t; i < e1; i += 256) {
    int c = col[i];
    int pos = atomicAdd(&tot[c >> 8], 1);
    tmp[pos] = make_int2(row[i], c);
  }
}

// ---------------------------------------------------------------------------
// k3: per-bucket CSR finalize (blocks < B) OR gemm1 tiles (blocks >= B,
// strided over all tiles). Decoupled so the slow CSR blocks don't serialize
// a gemm tile behind their CSR work.
// ---------------------------------------------------------------------------
__global__ __launch_bounds__(256)
void csr_gemm1_kernel(const int2* __restrict__ tmp, const int* __restrict__ bs,
                      int* __restrict__ rowp, float* __restrict__ dis,
                      float* __restrict__ dinv, int* __restrict__ ep, int n, int B,
                      const _Float16* __restrict__ Xh, const _Float16* __restrict__ W1t,
                      _Float16* __restrict__ Y) {
  int t = threadIdx.x, b = blockIdx.x;
  const int TG = gridDim.x;
  if (b < B) {
    __shared__ int h[256], lo[256], cur[256];
    h[t] = 0;
    __syncthreads();
    int s0 = bs[b], s1 = bs[b + 1];
    for (int i = s0 + t; i < s1; i += 256)
      atomicAdd(&h[tmp[i].y & 255], 1);
    __syncthreads();
    if (t == 0) {
      int run = 0;
      for (int cb = 0; cb < 256; ++cb) { lo[cb] = run; run += h[cb]; }
    }
    __syncthreads();
    cur[t] = lo[t];
    int node = (b << 8) + t;
    if (node < n) {
      int c = h[t];
      rowp[node] = s0 + lo[t];
      float d = (float)(c + 1);   // +1 self loop
      dinv[node] = 1.0f / d;
      dis[node]  = rsqrtf(d);
      if (node == n - 1) rowp[n] = s1;   // last bucket end == E
    }
    __syncthreads();
    for (int i = s0 + t; i < s1; i += 256) {
      int2 rc = tmp[i];
      int r = atomicAdd(&cur[rc.y & 255], 1);
      ep[s0 + r] = rc.x;
    }
  } else {
    const int G2 = TG - B;   // 586 gemm blocks cover TG tiles
    for (int tile = b - B; tile < TG; tile += G2)
      gemm_tile<128>(Xh, W1t, Y, n, tile, t);
  }
}

// ---------------------------------------------------------------------------
// k4: CH=128 aggregation, quarter scheme, 6 groups (24 edges) in flight,
// branch-free body. Writes packed epw[e] = {src, w} for the second pass.
// Self-row + deg_inv prefetched before the edge loop.
// ---------------------------------------------------------------------------
template<bool RELU>
__global__ __launch_bounds__(256)
void agg128h_kernel(const __half* __restrict__ xw, const int* __restrict__ row_ptr,
                    const int* __restrict__ ep, const float* __restrict__ dis,
                    int2* __restrict__ epw, const float* __restrict__ deg_inv,
                    const float* __restrict__ bias, __half* __restrict__ out, int n) {
  int wave = (blockIdx.x * 256 + threadIdx.x) >> 6;
  int lane = threadIdx.x & 63;
  if (wave >= n) return;
  const int node = wave;
  const int s0 = row_ptr[node], s1 = row_ptr[node + 1];
  const int sub = lane & 15;
  const int q = lane >> 4;
  const float disc = dis[node];
  // prefetch epilogue operands (overlap with gather chains)
  float di = 0.f; float4 sraw = make_float4(0.f, 0.f, 0.f, 0.f);
  if (q == 0) {
    di = deg_inv[node];
    sraw = ((const float4*)(xw + (size_t)node * 128))[sub];
  }
  float acc[2][8];
#pragma unroll
  for (int g = 0; g < 2; ++g)
#pragma unroll
    for (int j = 0; j < 8; ++j) acc[g][j] = 0.f;
  for (int e = s0; e < s1; e += 24) {
    int eg[6], sg[6];
#pragma unroll
    for (int g = 0; g < 6; ++g) {
      eg[g] = e + 4 * g + q;
      int cg = min(eg[g], s1 - 1);
      sg[g] = ep[cg];
    }
    float dg[6]; float4 raw[6];
#pragma unroll
    for (int g = 0; g < 6; ++g) {
      dg[g] = dis[sg[g]];
      raw[g] = ((const float4*)(xw + (size_t)sg[g] * 128))[sub];
    }
#pragma unroll
    for (int g = 0; g < 6; ++g) {
      bool ok = eg[g] < s1;
      if (sub == 0 && ok) epw[eg[g]] = make_int2(sg[g], __float_as_int(dg[g]));
      float wg = ok ? dg[g] * disc : 0.f;
      const __half2* hp = (const __half2*)&raw[g];
#pragma unroll
      for (int j = 0; j < 4; ++j) {
        float2 v = __half22float2(hp[j]);
        acc[g & 1][2 * j]     = fmaf(wg, v.x, acc[g & 1][2 * j]);
        acc[g & 1][2 * j + 1] = fmaf(wg, v.y, acc[g & 1][2 * j + 1]);
      }
    }
  }
#pragma unroll
  for (int j = 0; j < 8; ++j) {
    float s = acc[0][j] + acc[1][j];
    s += __shfl_xor(s, 16, 64);
    s += __shfl_xor(s, 32, 64);
    acc[0][j] = s;
  }
  if (q == 0) {
    const __half2* sp = (const __half2*)&sraw;
    const float4* bp = (const float4*)(bias + 8 * sub);
    float o[8];
#pragma unroll
    for (int j = 0; j < 4; ++j) {
      float2 sv = __half22float2(sp[j]);
      o[2 * j]     = acc[0][2 * j]     + sv.x * di;
      o[2 * j + 1] = acc[0][2 * j + 1] + sv.y * di;
    }
    float4 b0 = bp[0], b1v = bp[1];
    o[0] += b0.x; o[1] += b0.y; o[2] += b0.z; o[3] += b0.w;
    o[4] += b1v.x; o[5] += b1v.y; o[6] += b1v.z; o[7] += b1v.w;
    if (RELU) {
#pragma unroll
      for (int j = 0; j < 8; ++j) o[j] = fmaxf(o[j], 0.f);
    }
    __half2 h2[4];
#pragma unroll
    for (int j = 0; j < 4; ++j)
      h2[j] = __float22half2_rn(make_float2(o[2 * j], o[2 * j + 1]));
    *(float4*)(out + (size_t)node * 128 + 8 * sub) = *(const float4*)h2;
  }
}

// ---------------------------------------------------------------------------
// k6: CH=64 aggregation, OCT scheme, 4 groups (32 edges) in flight.
// One 8B packed {src, w} load per edge (epw from agg128).
// ---------------------------------------------------------------------------
template<bool RELU>
__global__ __launch_bounds__(256)
void agg64h_kernel(const __half* __restrict__ xw, const int* __restrict__ row_ptr,
                   const int2* __restrict__ epw, const float* __restrict__ dis,
                   const float* __restrict__ deg_inv, const float* __restrict__ bias,
                   __half* __restrict__ out, int n) {
  int wave = (blockIdx.x * 256 + threadIdx.x) >> 6;
  int lane = threadIdx.x & 63;
  if (wave >= n) return;
  const int node = wave;
  const int s0 = row_ptr[node], s1 = row_ptr[node + 1];
  const int sub = lane & 7;       // 8 lanes x 16B = 128B row (8 ch each)
  const int oct = lane >> 3;      // 8 edges per group
  const float disc = dis[node];
  // prefetch epilogue operands
  float di = 0.f; float4 sraw = make_float4(0.f, 0.f, 0.f, 0.f);
  if (oct == 0) {
    di = deg_inv[node];
    sraw = ((const float4*)(xw + (size_t)node * 64))[sub];
  }
  float acc[2][8];
#pragma unroll
  for (int g = 0; g < 2; ++g)
#pragma unroll
    for (int j = 0; j < 8; ++j) acc[g][j] = 0.f;
  for (int e = s0; e < s1; e += 32) {
    int eg[4]; int2 pw[4];
#pragma unroll
    for (int g = 0; g < 4; ++g) {
      eg[g] = e + 8 * g + oct;
      int cg = min(eg[g], s1 - 1);
      pw[g] = epw[cg];
    }
    float4 raw[4];
#pragma unroll
    for (int g = 0; g < 4; ++g)
      raw[g] = ((const float4*)(xw + (size_t)pw[g].x * 64))[sub];
#pragma unroll
    for (int g = 0; g < 4; ++g) {
      float wg = (eg[g] < s1) ? __int_as_float(pw[g].y) * disc : 0.f;
      const __half2* hp = (const __half2*)&raw[g];
#pragma unroll
      for (int j = 0; j < 4; ++j) {
        float2 v = __half22float2(hp[j]);
        acc[g & 1][2 * j]     = fmaf(wg, v.x, acc[g & 1][2 * j]);
        acc[g & 1][2 * j + 1] = fmaf(wg, v.y, acc[g & 1][2 * j + 1]);
      }
    }
  }
#pragma unroll
  for (int j = 0; j < 8; ++j) {
    float s = acc[0][j] + acc[1][j];
    s += __shfl_xor(s, 8, 64);
    s += __shfl_xor(s, 16, 64);
    s += __shfl_xor(s, 32, 64);
    acc[0][j] = s;
  }
  if (oct == 0) {
    const __half2* sp = (const __half2*)&sraw;
    const float4* bp = (const float4*)(bias + 8 * sub);
    float o[8];
#pragma unroll
    for (int j = 0; j < 4; ++j) {
      float2 sv = __half22float2(sp[j]);
      o[2 * j]     = acc[0][2 * j]     + sv.x * di;
      o[2 * j + 1] = acc[0][2 * j + 1] + sv.y * di;
    }
    float4 b0 = bp[0], b1v = bp[1];
    o[0] += b0.x; o[1] += b0.y; o[2] += b0.z; o[3] += b0.w;
    o[4] += b1v.x; o[5] += b1v.y; o[6] += b1v.z; o[7] += b1v.w;
    if (RELU) {
#pragma unroll
      for (int j = 0; j < 8; ++j) o[j] = fmaxf(o[j], 0.f);
    }
    __half2 h2[4];
#pragma unroll
    for (int j = 0; j < 4; ++j)
      h2[j] = __float22half2_rn(make_float2(o[2 * j], o[2 * j + 1]));
    *(float4*)(out + (size_t)node * 64 + 8 * sub) = *(const float4*)h2;
  }
}

// k5: standalone gemm2.
template<int M>
__global__ __launch_bounds__(256)
void gemm_mfma_kernel(const _Float16* __restrict__ Xh,
                      const _Float16* __restrict__ Wt,
                      _Float16* __restrict__ Y, int N) {
  gemm_tile<M>(Xh, Wt, Y, N, blockIdx.x, threadIdx.x);
}

// ---------------------------------------------------------------------------
// k7: decode — 12 pairs per wave, gathers batched before reductions (ILP 24).
// ---------------------------------------------------------------------------
__global__ __launch_bounds__(256)
void decode_kernel(const __half* __restrict__ z, const int* __restrict__ eli,
                   float* __restrict__ out, int nl) {
  int wave = (blockIdx.x * 256 + threadIdx.x) >> 6;
  int lane = threadIdx.x & 63;
  int p0 = wave * 12;
  if (p0 >= nl) return;
  int sub = lane & 31;
  float2 v[12];
#pragma unroll
  for (int j = 0; j < 12; ++j) {
    int p = min(p0 + j, nl - 1);
    int src = eli[p];
    int dst = eli[nl + p];
    int node = (lane < 32) ? src : dst;
    v[j] = __half22float2(((const __half2*)(z + (size_t)node * 64))[sub]);
  }
#pragma unroll
  for (int j = 0; j < 12; ++j) {
    int p = p0 + j;
    float ox = __shfl_xor(v[j].x, 32, 64);
    float oy = __shfl_xor(v[j].y, 32, 64);
    float pr = v[j].x * ox + v[j].y * oy;
#pragma unroll
    for (int m = 16; m >= 1; m >>= 1) pr += __shfl_xor(pr, m, 64);
    if (lane == 0 && p < nl) out[p] = pr;
  }
}

// ---------------------------------------------------------------------------

extern "C" void kernel_launch(void* const* d_in, const int* in_sizes, int n_in,
                              void* d_out, int out_size, void* d_ws, size_t ws_size,
                              hipStream_t stream) {
  const float* x  = (const float*)d_in[0];
  const float* W1 = (const float*)d_in[1];
  const float* b1 = (const float*)d_in[2];
  const float* W2 = (const float*)d_in[3];
  const float* b2 = (const float*)d_in[4];
  const int* eidx = (const int*)d_in[5];
  const int* eli  = (const int*)d_in[6];
  const int N  = in_sizes[0] / 128;
  const int E  = in_sizes[5] / 2;
  const int NL = in_sizes[6] / 2;
  float* out = (float*)d_out;

  char* ws = (char*)d_ws;
  size_t off = 0;
  auto alloc = [&](size_t bytes) -> char* {
    char* p = ws + off;
    off = (off + bytes + 255) & ~(size_t)255;
    return p;
  };
  const int B = (N + 255) / 256;        // buckets (col>>8); needs N <= 65536
  const int chunk = (E + NBLK - 1) / NBLK;
  float*    dis   = (float*)   alloc((size_t)N * 4);
  float*    dinv  = (float*)   alloc((size_t)N * 4);
  int*      rowp  = (int*)     alloc((size_t)(N + 1) * 4);
  int*      bhist = (int*)     alloc((size_t)NBLK * B * 4);
  int*      bs    = (int*)     alloc((size_t)(B + 1) * 4);
  int2*     tmp   = (int2*)    alloc((size_t)E * 8);
  int*      ep    = (int*)     alloc((size_t)E * 4);
  int2*     epw   = (int2*)    alloc((size_t)E * 8);
  _Float16* Xh    = (_Float16*)alloc((size_t)N * 128 * 2);
  _Float16* W1t   = (_Float16*)alloc((size_t)128 * 128 * 2);
  _Float16* W2t   = (_Float16*)alloc((size_t)64 * 128 * 2);
  __half*   bufA  = (__half*)  alloc((size_t)N * 128 * 2);
  __half*   bufB  = (__half*)  alloc((size_t)N * 128 * 2);
  __half*   bufC  = (__half*)  alloc((size_t)N * 64 * 2);
  __half*   z     = (__half*)  alloc((size_t)N * 64 * 2);
  (void)ws_size; (void)n_in; (void)out_size;

  const int* row = eidx;      // edge_index[0]
  const int* col = eidx + E;  // edge_index[1]
  const int n4 = N * 32;      // N*128/4 float4 groups
  const int TG = (N + 63) / 64;  // gemm tiles (782) > B (196)

  // k1: prep + hist fused
  prep_hist_kernel<<<2048, 256, 0, stream>>>(x, W1, W2, Xh, W1t, W2t, n4,
                                             col, bhist, E, chunk, B);
  // k2: scatter with fused base computation
  scatter_base_kernel<<<NBLK, 256, 0, stream>>>(row, col, bhist, tmp, bs, E, chunk, B);
  // k3: CSR finalize (blocks < B) | gemm1 tiles (blocks >= B)
  csr_gemm1_kernel<<<TG, 256, 0, stream>>>(tmp, bs, rowp, dis, dinv, ep, N, B,
                                           Xh, W1t, (_Float16*)bufA);
  // k4: bufB = half(relu(agg(bufA)+dinv*bufA+b1)); writes packed epw[]
  agg128h_kernel<true><<<(N + 3) / 4, 256, 0, stream>>>(bufA, rowp, ep, dis, epw,
                                                        dinv, b1, bufB, N);
  // k5: bufC = half(bufB@W2)
  gemm_mfma_kernel<64><<<TG, 256, 0, stream>>>((const _Float16*)bufB, W2t,
                                               (_Float16*)bufC, N);
  // k6: z = half(agg(bufC)+dinv*bufC+b2) using packed epw[]
  agg64h_kernel<false><<<(N + 3) / 4, 256, 0, stream>>>(bufC, rowp, epw, dis,
                                                        dinv, b2, z, N);
  // k7: decode (12 pairs/wave)
  decode_kernel<<<(NL + 47) / 48, 256, 0, stream>>>(z, eli, out, NL);
}

// Round 9
// 217.031 us; speedup vs baseline: 1.0807x; 1.0232x over previous
//
#include <hip/hip_runtime.h>
#include <hip/hip_bf16.h>
#include <hip/hip_fp16.h>

// ---------------------------------------------------------------------------
// GCN link prediction (math fp32, fp16 tables, MFMA GEMMs).
// Round 23: 7 dispatches; CSR-build chain slimmed:
//  1. tmp packed to 4B/edge: row(16b) | (col&255)(8b)<<16  (N<65536).
//     Halves k2 scattered writes and k3's two read passes.
//  2. bhist transposed to bucket-major; scatter_base's per-thread prefix
//     loop reads it as 64 int4 loads (was 256 strided scalar loads).
//   k1 prep+hist   (2048 blocks)
//   k2 scatter+base(256 blocks, vectorized prefix, packed tmp)
//   k3 csr+gemm1   (782 blocks, decoupled roles, packed tmp)
//   k4 agg128+relu (12500 blocks, 6 groups)
//   k5 gemm2       (782 blocks)
//   k6 agg64       (12500 blocks, 4 groups, packed epw payload)
//   k7 decode      (4167 blocks, 12 pairs/wave)
// ---------------------------------------------------------------------------

typedef _Float16 half8 __attribute__((ext_vector_type(8)));
typedef _Float16 half4v __attribute__((ext_vector_type(4)));
typedef float   floatx4 __attribute__((ext_vector_type(4)));

#define NBLK 256  // blocks for edge-chunk passes (hist/scatter chunking)

// ---------------------------------------------------------------------------

template<int M>
__device__ __forceinline__ void gemm_tile(const _Float16* __restrict__ Xh,
                                          const _Float16* __restrict__ Wt,
                                          _Float16* __restrict__ Y,
                                          int N, int tile, int t) {
  constexpr int K = 128;
  constexpr int CT = M / 16;
  const int lane = t & 63;
  const int i16 = lane & 15;
  const int quad = lane >> 4;
  const int row0 = tile * 64 + (t >> 6) * 16;
  int arow = row0 + i16;
  if (arow >= N) arow = N - 1;
  const _Float16* aptr = Xh + (size_t)arow * K + quad * 8;
  floatx4 acc[CT];
#pragma unroll
  for (int c = 0; c < CT; ++c) acc[c] = (floatx4){0.f, 0.f, 0.f, 0.f};
#pragma unroll
  for (int k0 = 0; k0 < K; k0 += 32) {
    half8 a = *(const half8*)(aptr + k0);
#pragma unroll
    for (int c = 0; c < CT; ++c) {
      half8 b = *(const half8*)(Wt + (size_t)(c * 16 + i16) * K + quad * 8 + k0);
      acc[c] = __builtin_amdgcn_mfma_f32_16x16x32_f16(a, b, acc[c], 0, 0, 0);
    }
  }
#pragma unroll
  for (int c = 0; c < CT; ++c) {
#pragma unroll
    for (int r = 0; r < 4; ++r) {
      int gr = row0 + quad * 4 + r;
      if (gr < N) Y[(size_t)gr * M + c * 16 + i16] = (_Float16)acc[c][r];
    }
  }
}

// ---------------------------------------------------------------------------
// k1: fused prep + per-chunk bucket histogram (bhist bucket-major).
// ---------------------------------------------------------------------------
__global__ __launch_bounds__(256)
void prep_hist_kernel(const float* __restrict__ x, const float* __restrict__ W1,
                      const float* __restrict__ W2, _Float16* __restrict__ Xh,
                      _Float16* __restrict__ W1t, _Float16* __restrict__ W2t,
                      int n4, const int* __restrict__ col,
                      int* __restrict__ bhist, int ne, int chunk, int B) {
  int t = threadIdx.x, blk = blockIdx.x;
  if (blk < NBLK) {   // histogram part
    __shared__ int h[256];
    for (int b = t; b < B; b += 256) h[b] = 0;
    __syncthreads();
    int e0 = blk * chunk, e1 = min(ne, e0 + chunk);
    for (int i = e0 + t; i < e1; i += 256)
      atomicAdd(&h[col[i] >> 8], 1);
    __syncthreads();
    for (int b = t; b < B; b += 256) bhist[b * NBLK + blk] = h[b];  // bucket-major
  }
  // prep part: all blocks grid-stride
  const int gs = gridDim.x * 256;
  for (int i = blk * 256 + t; i < n4; i += gs) {
    float4 v = ((const float4*)x)[i];
    half4v h4; h4[0] = (_Float16)v.x; h4[1] = (_Float16)v.y;
    h4[2] = (_Float16)v.z; h4[3] = (_Float16)v.w;
    ((half4v*)Xh)[i] = h4;
    if (i < 128 * 128) { int k = i >> 7, n = i & 127; W1t[(size_t)n * 128 + k] = (_Float16)W1[i]; }
    if (i < 128 * 64)  { int k = i >> 6, n = i & 63;  W2t[(size_t)n * 128 + k] = (_Float16)W2[i]; }
  }
}

// ---------------------------------------------------------------------------
// k2: scatter with base computation fused. Per-thread prefix over bucket-major
// bhist as int4 (64 loads); packed 4B tmp entries.
// ---------------------------------------------------------------------------
__global__ __launch_bounds__(256)
void scatter_base_kernel(const int* __restrict__ row, const int* __restrict__ col,
                         const int* __restrict__ bhist, unsigned int* __restrict__ tmp,
                         int* __restrict__ bs, int ne, int chunk, int B) {
  __shared__ int tot[256], myp[256], start[257];
  int t = threadIdx.x, blk = blockIdx.x;
  if (t < B) {
    int s = 0, sp = 0;
    const int4* bp4 = (const int4*)(bhist + t * NBLK);
#pragma unroll 4
    for (int i2 = 0; i2 < NBLK / 4; ++i2) {
      int4 v = bp4[i2];
      int b4 = i2 * 4;
      s += v.x + v.y + v.z + v.w;
      sp += (b4     < blk ? v.x : 0) + (b4 + 1 < blk ? v.y : 0)
          + (b4 + 2 < blk ? v.z : 0) + (b4 + 3 < blk ? v.w : 0);
    }
    tot[t] = s; myp[t] = sp;
  }
  __syncthreads();
  if (t == 0) {
    int run = 0;
    for (int b = 0; b < B; ++b) { start[b] = run; run += tot[b]; }
    start[B] = run;
  }
  __syncthreads();
  if (blk == 0 && t <= B) bs[t] = start[t];
  if (t < B) tot[t] = start[t] + myp[t];   // reuse tot[] as this block's cursors
  __syncthreads();
  int e0 = blk * chunk, e1 = min(ne, e0 + chunk);
  for (int i = e0 + t; i < e1; i += 256) {
    int c = col[i];
    int pos = atomicAdd(&tot[c >> 8], 1);
    tmp[pos] = (unsigned int)row[i] | ((unsigned int)(c & 255) << 16);
  }
}

// ---------------------------------------------------------------------------
// k3: per-bucket CSR finalize (blocks < B) OR gemm1 tiles (blocks >= B).
// tmp entries are packed: row = v & 0xFFFF, colLow = (v >> 16) & 255.
// ---------------------------------------------------------------------------
__global__ __launch_bounds__(256)
void csr_gemm1_kernel(const unsigned int* __restrict__ tmp, const int* __restrict__ bs,
                      int* __restrict__ rowp, float* __restrict__ dis,
                      float* __restrict__ dinv, int* __restrict__ ep, int n, int B,
                      const _Float16* __restrict__ Xh, const _Float16* __restrict__ W1t,
                      _Float16* __restrict__ Y) {
  int t = threadIdx.x, b = blockIdx.x;
  const int TG = gridDim.x;
  if (b < B) {
    __shared__ int h[256], lo[256], cur[256];
    h[t] = 0;
    __syncthreads();
    int s0 = bs[b], s1 = bs[b + 1];
    for (int i = s0 + t; i < s1; i += 256)
      atomicAdd(&h[(tmp[i] >> 16) & 255], 1);
    __syncthreads();
    if (t == 0) {
      int run = 0;
      for (int cb = 0; cb < 256; ++cb) { lo[cb] = run; run += h[cb]; }
    }
    __syncthreads();
    cur[t] = lo[t];
    int node = (b << 8) + t;
    if (node < n) {
      int c = h[t];
      rowp[node] = s0 + lo[t];
      float d = (float)(c + 1);   // +1 self loop
      dinv[node] = 1.0f / d;
      dis[node]  = rsqrtf(d);
      if (node == n - 1) rowp[n] = s1;   // last bucket end == E
    }
    __syncthreads();
    for (int i = s0 + t; i < s1; i += 256) {
      unsigned int v = tmp[i];
      int r = atomicAdd(&cur[(v >> 16) & 255], 1);
      ep[s0 + r] = (int)(v & 0xFFFFu);
    }
  } else {
    const int G2 = TG - B;   // 586 gemm blocks cover TG tiles
    for (int tile = b - B; tile < TG; tile += G2)
      gemm_tile<128>(Xh, W1t, Y, n, tile, t);
  }
}

// ---------------------------------------------------------------------------
// k4: CH=128 aggregation, quarter scheme, 6 groups (24 edges) in flight,
// branch-free body. Writes packed epw[e] = {src, w} for the second pass.
// Self-row + deg_inv prefetched before the edge loop.
// ---------------------------------------------------------------------------
template<bool RELU>
__global__ __launch_bounds__(256)
void agg128h_kernel(const __half* __restrict__ xw, const int* __restrict__ row_ptr,
                    const int* __restrict__ ep, const float* __restrict__ dis,
                    int2* __restrict__ epw, const float* __restrict__ deg_inv,
                    const float* __restrict__ bias, __half* __restrict__ out, int n) {
  int wave = (blockIdx.x * 256 + threadIdx.x) >> 6;
  int lane = threadIdx.x & 63;
  if (wave >= n) return;
  const int node = wave;
  const int s0 = row_ptr[node], s1 = row_ptr[node + 1];
  const int sub = lane & 15;
  const int q = lane >> 4;
  const float disc = dis[node];
  // prefetch epilogue operands (overlap with gather chains)
  float di = 0.f; float4 sraw = make_float4(0.f, 0.f, 0.f, 0.f);
  if (q == 0) {
    di = deg_inv[node];
    sraw = ((const float4*)(xw + (size_t)node * 128))[sub];
  }
  float acc[2][8];
#pragma unroll
  for (int g = 0; g < 2; ++g)
#pragma unroll
    for (int j = 0; j < 8; ++j) acc[g][j] = 0.f;
  for (int e = s0; e < s1; e += 24) {
    int eg[6], sg[6];
#pragma unroll
    for (int g = 0; g < 6; ++g) {
      eg[g] = e + 4 * g + q;
      int cg = min(eg[g], s1 - 1);
      sg[g] = ep[cg];
    }
    float dg[6]; float4 raw[6];
#pragma unroll
    for (int g = 0; g < 6; ++g) {
      dg[g] = dis[sg[g]];
      raw[g] = ((const float4*)(xw + (size_t)sg[g] * 128))[sub];
    }
#pragma unroll
    for (int g = 0; g < 6; ++g) {
      bool ok = eg[g] < s1;
      if (sub == 0 && ok) epw[eg[g]] = make_int2(sg[g], __float_as_int(dg[g]));
      float wg = ok ? dg[g] * disc : 0.f;
      const __half2* hp = (const __half2*)&raw[g];
#pragma unroll
      for (int j = 0; j < 4; ++j) {
        float2 v = __half22float2(hp[j]);
        acc[g & 1][2 * j]     = fmaf(wg, v.x, acc[g & 1][2 * j]);
        acc[g & 1][2 * j + 1] = fmaf(wg, v.y, acc[g & 1][2 * j + 1]);
      }
    }
  }
#pragma unroll
  for (int j = 0; j < 8; ++j) {
    float s = acc[0][j] + acc[1][j];
    s += __shfl_xor(s, 16, 64);
    s += __shfl_xor(s, 32, 64);
    acc[0][j] = s;
  }
  if (q == 0) {
    const __half2* sp = (const __half2*)&sraw;
    const float4* bp = (const float4*)(bias + 8 * sub);
    float o[8];
#pragma unroll
    for (int j = 0; j < 4; ++j) {
      float2 sv = __half22float2(sp[j]);
      o[2 * j]     = acc[0][2 * j]     + sv.x * di;
      o[2 * j + 1] = acc[0][2 * j + 1] + sv.y * di;
    }
    float4 b0 = bp[0], b1v = bp[1];
    o[0] += b0.x; o[1] += b0.y; o[2] += b0.z; o[3] += b0.w;
    o[4] += b1v.x; o[5] += b1v.y; o[6] += b1v.z; o[7] += b1v.w;
    if (RELU) {
#pragma unroll
      for (int j = 0; j < 8; ++j) o[j] = fmaxf(o[j], 0.f);
    }
    __half2 h2[4];
#pragma unroll
    for (int j = 0; j < 4; ++j)
      h2[j] = __float22half2_rn(make_float2(o[2 * j], o[2 * j + 1]));
    *(float4*)(out + (size_t)node * 128 + 8 * sub) = *(const float4*)h2;
  }
}

// ---------------------------------------------------------------------------
// k6: CH=64 aggregation, OCT scheme, 4 groups (32 edges) in flight.
// One 8B packed {src, w} load per edge (epw from agg128).
// ---------------------------------------------------------------------------
template<bool RELU>
__global__ __launch_bounds__(256)
void agg64h_kernel(const __half* __restrict__ xw, const int* __restrict__ row_ptr,
                   const int2* __restrict__ epw, const float* __restrict__ dis,
                   const float* __restrict__ deg_inv, const float* __restrict__ bias,
                   __half* __restrict__ out, int n) {
  int wave = (blockIdx.x * 256 + threadIdx.x) >> 6;
  int lane = threadIdx.x & 63;
  if (wave >= n) return;
  const int node = wave;
  const int s0 = row_ptr[node], s1 = row_ptr[node + 1];
  const int sub = lane & 7;       // 8 lanes x 16B = 128B row (8 ch each)
  const int oct = lane >> 3;      // 8 edges per group
  const float disc = dis[node];
  // prefetch epilogue operands
  float di = 0.f; float4 sraw = make_float4(0.f, 0.f, 0.f, 0.f);
  if (oct == 0) {
    di = deg_inv[node];
    sraw = ((const float4*)(xw + (size_t)node * 64))[sub];
  }
  float acc[2][8];
#pragma unroll
  for (int g = 0; g < 2; ++g)
#pragma unroll
    for (int j = 0; j < 8; ++j) acc[g][j] = 0.f;
  for (int e = s0; e < s1; e += 32) {
    int eg[4]; int2 pw[4];
#pragma unroll
    for (int g = 0; g < 4; ++g) {
      eg[g] = e + 8 * g + oct;
      int cg = min(eg[g], s1 - 1);
      pw[g] = epw[cg];
    }
    float4 raw[4];
#pragma unroll
    for (int g = 0; g < 4; ++g)
      raw[g] = ((const float4*)(xw + (size_t)pw[g].x * 64))[sub];
#pragma unroll
    for (int g = 0; g < 4; ++g) {
      float wg = (eg[g] < s1) ? __int_as_float(pw[g].y) * disc : 0.f;
      const __half2* hp = (const __half2*)&raw[g];
#pragma unroll
      for (int j = 0; j < 4; ++j) {
        float2 v = __half22float2(hp[j]);
        acc[g & 1][2 * j]     = fmaf(wg, v.x, acc[g & 1][2 * j]);
        acc[g & 1][2 * j + 1] = fmaf(wg, v.y, acc[g & 1][2 * j + 1]);
      }
    }
  }
#pragma unroll
  for (int j = 0; j < 8; ++j) {
    float s = acc[0][j] + acc[1][j];
    s += __shfl_xor(s, 8, 64);
    s += __shfl_xor(s, 16, 64);
    s += __shfl_xor(s, 32, 64);
    acc[0][j] = s;
  }
  if (oct == 0) {
    const __half2* sp = (const __half2*)&sraw;
    const float4* bp = (const float4*)(bias + 8 * sub);
    float o[8];
#pragma unroll
    for (int j = 0; j < 4; ++j) {
      float2 sv = __half22float2(sp[j]);
      o[2 * j]     = acc[0][2 * j]     + sv.x * di;
      o[2 * j + 1] = acc[0][2 * j + 1] + sv.y * di;
    }
    float4 b0 = bp[0], b1v = bp[1];
    o[0] += b0.x; o[1] += b0.y; o[2] += b0.z; o[3] += b0.w;
    o[4] += b1v.x; o[5] += b1v.y; o[6] += b1v.z; o[7] += b1v.w;
    if (RELU) {
#pragma unroll
      for (int j = 0; j < 8; ++j) o[j] = fmaxf(o[j], 0.f);
    }
    __half2 h2[4];
#pragma unroll
    for (int j = 0; j < 4; ++j)
      h2[j] = __float22half2_rn(make_float2(o[2 * j], o[2 * j + 1]));
    *(float4*)(out + (size_t)node * 64 + 8 * sub) = *(const float4*)h2;
  }
}

// k5: standalone gemm2.
template<int M>
__global__ __launch_bounds__(256)
void gemm_mfma_kernel(const _Float16* __restrict__ Xh,
                      const _Float16* __restrict__ Wt,
                      _Float16* __restrict__ Y, int N) {
  gemm_tile<M>(Xh, Wt, Y, N, blockIdx.x, threadIdx.x);
}

// ---------------------------------------------------------------------------
// k7: decode — 12 pairs per wave, gathers batched before reductions (ILP 24).
// ---------------------------------------------------------------------------
__global__ __launch_bounds__(256)
void decode_kernel(const __half* __restrict__ z, const int* __restrict__ eli,
                   float* __restrict__ out, int nl) {
  int wave = (blockIdx.x * 256 + threadIdx.x) >> 6;
  int lane = threadIdx.x & 63;
  int p0 = wave * 12;
  if (p0 >= nl) return;
  int sub = lane & 31;
  float2 v[12];
#pragma unroll
  for (int j = 0; j < 12; ++j) {
    int p = min(p0 + j, nl - 1);
    int src = eli[p];
    int dst = eli[nl + p];
    int node = (lane < 32) ? src : dst;
    v[j] = __half22float2(((const __half2*)(z + (size_t)node * 64))[sub]);
  }
#pragma unroll
  for (int j = 0; j < 12; ++j) {
    int p = p0 + j;
    float ox = __shfl_xor(v[j].x, 32, 64);
    float oy = __shfl_xor(v[j].y, 32, 64);
    float pr = v[j].x * ox + v[j].y * oy;
#pragma unroll
    for (int m = 16; m >= 1; m >>= 1) pr += __shfl_xor(pr, m, 64);
    if (lane == 0 && p < nl) out[p] = pr;
  }
}

// ---------------------------------------------------------------------------

extern "C" void kernel_launch(void* const* d_in, const int* in_sizes, int n_in,
                              void* d_out, int out_size, void* d_ws, size_t ws_size,
                              hipStream_t stream) {
  const float* x  = (const float*)d_in[0];
  const float* W1 = (const float*)d_in[1];
  const float* b1 = (const float*)d_in[2];
  const float* W2 = (const float*)d_in[3];
  const float* b2 = (const float*)d_in[4];
  const int* eidx = (const int*)d_in[5];
  const int* eli  = (const int*)d_in[6];
  const int N  = in_sizes[0] / 128;
  const int E  = in_sizes[5] / 2;
  const int NL = in_sizes[6] / 2;
  float* out = (float*)d_out;

  char* ws = (char*)d_ws;
  size_t off = 0;
  auto alloc = [&](size_t bytes) -> char* {
    char* p = ws + off;
    off = (off + bytes + 255) & ~(size_t)255;
    return p;
  };
  const int B = (N + 255) / 256;        // buckets (col>>8); needs N <= 65536
  const int chunk = (E + NBLK - 1) / NBLK;
  float*        dis   = (float*)       alloc((size_t)N * 4);
  float*        dinv  = (float*)       alloc((size_t)N * 4);
  int*          rowp  = (int*)         alloc((size_t)(N + 1) * 4);
  int*          bhist = (int*)         alloc((size_t)NBLK * B * 4);
  int*          bs    = (int*)         alloc((size_t)(B + 1) * 4);
  unsigned int* tmp   = (unsigned int*)alloc((size_t)E * 4);
  int*          ep    = (int*)         alloc((size_t)E * 4);
  int2*         epw   = (int2*)        alloc((size_t)E * 8);
  _Float16*     Xh    = (_Float16*)    alloc((size_t)N * 128 * 2);
  _Float16*     W1t   = (_Float16*)    alloc((size_t)128 * 128 * 2);
  _Float16*     W2t   = (_Float16*)    alloc((size_t)64 * 128 * 2);
  __half*       bufA  = (__half*)      alloc((size_t)N * 128 * 2);
  __half*       bufB  = (__half*)      alloc((size_t)N * 128 * 2);
  __half*       bufC  = (__half*)      alloc((size_t)N * 64 * 2);
  __half*       z     = (__half*)      alloc((size_t)N * 64 * 2);
  (void)ws_size; (void)n_in; (void)out_size;

  const int* row = eidx;      // edge_index[0]
  const int* col = eidx + E;  // edge_index[1]
  const int n4 = N * 32;      // N*128/4 float4 groups
  const int TG = (N + 63) / 64;  // gemm tiles (782) > B (196)

  // k1: prep + hist fused (bhist bucket-major)
  prep_hist_kernel<<<2048, 256, 0, stream>>>(x, W1, W2, Xh, W1t, W2t, n4,
                                             col, bhist, E, chunk, B);
  // k2: scatter with fused base computation (vectorized prefix, packed tmp)
  scatter_base_kernel<<<NBLK, 256, 0, stream>>>(row, col, bhist, tmp, bs, E, chunk, B);
  // k3: CSR finalize (blocks < B) | gemm1 tiles (blocks >= B)
  csr_gemm1_kernel<<<TG, 256, 0, stream>>>(tmp, bs, rowp, dis, dinv, ep, N, B,
                                           Xh, W1t, (_Float16*)bufA);
  // k4: bufB = half(relu(agg(bufA)+dinv*bufA+b1)); writes packed epw[]
  agg128h_kernel<true><<<(N + 3) / 4, 256, 0, stream>>>(bufA, rowp, ep, dis, epw,
                                                        dinv, b1, bufB, N);
  // k5: bufC = half(bufB@W2)
  gemm_mfma_kernel<64><<<TG, 256, 0, stream>>>((const _Float16*)bufB, W2t,
                                               (_Float16*)bufC, N);
  // k6: z = half(agg(bufC)+dinv*bufC+b2) using packed epw[]
  agg64h_kernel<false><<<(N + 3) / 4, 256, 0, stream>>>(bufC, rowp, epw, dis,
                                                        dinv, b2, z, N);
  // k7: decode (12 pairs/wave)
  decode_kernel<<<(NL + 47) / 48, 256, 0, stream>>>(z, eli, out, NL);
}

// Round 10
// 210.005 us; speedup vs baseline: 1.1169x; 1.0335x over previous
//
#include <hip/hip_runtime.h>
#include <hip/hip_bf16.h>
#include <hip/hip_fp16.h>

// ---------------------------------------------------------------------------
// GCN link prediction (math fp32, fp16 tables, MFMA GEMMs).
// Round 24: 7 dispatches.
//  1. Xh eliminated: gemm1 reads fp32 x directly, converts in-register
//     (saves 25.6MB: prep's x read + Xh write + gemm1's Xh read).
//     k1 shrinks to hist + W1t/W2t transposes (256 blocks).
//  2. ep narrowed to ushort (N<65536): agg128 index reads halve.
//  3. epw packed to 4B {src:u16, w:fp16}: agg64 payload load halves.
//   k1 hist+Wt     (256 blocks)
//   k2 scatter+base(256 blocks, vectorized prefix, packed tmp)
//   k3 csr+gemm1   (782 blocks, decoupled roles; gemm1 from fp32 x)
//   k4 agg128+relu (12500 blocks, 6 groups, ushort ep)
//   k5 gemm2       (782 blocks)
//   k6 agg64       (12500 blocks, 4 groups, 4B packed epw)
//   k7 decode      (4167 blocks, 12 pairs/wave)
// ---------------------------------------------------------------------------

typedef _Float16 half8 __attribute__((ext_vector_type(8)));
typedef float   floatx4 __attribute__((ext_vector_type(4)));

#define NBLK 256  // blocks for edge-chunk passes (hist/scatter chunking)

// ---------------------------------------------------------------------------
// fp16-input gemm tile (used for gemm2).
// ---------------------------------------------------------------------------
template<int M>
__device__ __forceinline__ void gemm_tile(const _Float16* __restrict__ Xh,
                                          const _Float16* __restrict__ Wt,
                                          _Float16* __restrict__ Y,
                                          int N, int tile, int t) {
  constexpr int K = 128;
  constexpr int CT = M / 16;
  const int lane = t & 63;
  const int i16 = lane & 15;
  const int quad = lane >> 4;
  const int row0 = tile * 64 + (t >> 6) * 16;
  int arow = row0 + i16;
  if (arow >= N) arow = N - 1;
  const _Float16* aptr = Xh + (size_t)arow * K + quad * 8;
  floatx4 acc[CT];
#pragma unroll
  for (int c = 0; c < CT; ++c) acc[c] = (floatx4){0.f, 0.f, 0.f, 0.f};
#pragma unroll
  for (int k0 = 0; k0 < K; k0 += 32) {
    half8 a = *(const half8*)(aptr + k0);
#pragma unroll
    for (int c = 0; c < CT; ++c) {
      half8 b = *(const half8*)(Wt + (size_t)(c * 16 + i16) * K + quad * 8 + k0);
      acc[c] = __builtin_amdgcn_mfma_f32_16x16x32_f16(a, b, acc[c], 0, 0, 0);
    }
  }
#pragma unroll
  for (int c = 0; c < CT; ++c) {
#pragma unroll
    for (int r = 0; r < 4; ++r) {
      int gr = row0 + quad * 4 + r;
      if (gr < N) Y[(size_t)gr * M + c * 16 + i16] = (_Float16)acc[c][r];
    }
  }
}

// ---------------------------------------------------------------------------
// fp32-input gemm1 tile: reads x rows as float4 pairs, converts in-register.
// ---------------------------------------------------------------------------
__device__ __forceinline__ void gemm1_tile_f32(const float* __restrict__ X,
                                               const _Float16* __restrict__ Wt,
                                               _Float16* __restrict__ Y,
                                               int N, int tile, int t) {
  constexpr int K = 128;
  constexpr int CT = 8;   // M = 128
  const int lane = t & 63;
  const int i16 = lane & 15;
  const int quad = lane >> 4;
  const int row0 = tile * 64 + (t >> 6) * 16;
  int arow = row0 + i16;
  if (arow >= N) arow = N - 1;
  const float* aptr = X + (size_t)arow * K + quad * 8;
  floatx4 acc[CT];
#pragma unroll
  for (int c = 0; c < CT; ++c) acc[c] = (floatx4){0.f, 0.f, 0.f, 0.f};
#pragma unroll
  for (int k0 = 0; k0 < K; k0 += 32) {
    float4 a0 = *(const float4*)(aptr + k0);
    float4 a1 = *(const float4*)(aptr + k0 + 4);
    half8 a;
    a[0] = (_Float16)a0.x; a[1] = (_Float16)a0.y;
    a[2] = (_Float16)a0.z; a[3] = (_Float16)a0.w;
    a[4] = (_Float16)a1.x; a[5] = (_Float16)a1.y;
    a[6] = (_Float16)a1.z; a[7] = (_Float16)a1.w;
#pragma unroll
    for (int c = 0; c < CT; ++c) {
      half8 b = *(const half8*)(Wt + (size_t)(c * 16 + i16) * K + quad * 8 + k0);
      acc[c] = __builtin_amdgcn_mfma_f32_16x16x32_f16(a, b, acc[c], 0, 0, 0);
    }
  }
#pragma unroll
  for (int c = 0; c < CT; ++c) {
#pragma unroll
    for (int r = 0; r < 4; ++r) {
      int gr = row0 + quad * 4 + r;
      if (gr < N) Y[(size_t)gr * 128 + c * 16 + i16] = (_Float16)acc[c][r];
    }
  }
}

// ---------------------------------------------------------------------------
// k1: per-chunk bucket histogram (bucket-major) + W1t/W2t transposes.
// ---------------------------------------------------------------------------
__global__ __launch_bounds__(256)
void hist_prep_kernel(const float* __restrict__ W1, const float* __restrict__ W2,
                      _Float16* __restrict__ W1t, _Float16* __restrict__ W2t,
                      const int* __restrict__ col, int* __restrict__ bhist,
                      int ne, int chunk, int B) {
  int t = threadIdx.x, blk = blockIdx.x;
  {
    __shared__ int h[256];
    for (int b = t; b < B; b += 256) h[b] = 0;
    __syncthreads();
    int e0 = blk * chunk, e1 = min(ne, e0 + chunk);
    for (int i = e0 + t; i < e1; i += 256)
      atomicAdd(&h[col[i] >> 8], 1);
    __syncthreads();
    for (int b = t; b < B; b += 256) bhist[b * NBLK + blk] = h[b];  // bucket-major
  }
  int i = blk * 256 + t;
  if (i < 128 * 128) { int k = i >> 7, n = i & 127; W1t[(size_t)n * 128 + k] = (_Float16)W1[i]; }
  if (i < 128 * 64)  { int k = i >> 6, n = i & 63;  W2t[(size_t)n * 128 + k] = (_Float16)W2[i]; }
}

// ---------------------------------------------------------------------------
// k2: scatter with base computation fused. Per-thread prefix over bucket-major
// bhist as int4 (64 loads); packed 4B tmp entries.
// ---------------------------------------------------------------------------
__global__ __launch_bounds__(256)
void scatter_base_kernel(const int* __restrict__ row, const int* __restrict__ col,
                         const int* __restrict__ bhist, unsigned int* __restrict__ tmp,
                         int* __restrict__ bs, int ne, int chunk, int B) {
  __shared__ int tot[256], myp[256], start[257];
  int t = threadIdx.x, blk = blockIdx.x;
  if (t < B) {
    int s = 0, sp = 0;
    const int4* bp4 = (const int4*)(bhist + t * NBLK);
#pragma unroll 4
    for (int i2 = 0; i2 < NBLK / 4; ++i2) {
      int4 v = bp4[i2];
      int b4 = i2 * 4;
      s += v.x + v.y + v.z + v.w;
      sp += (b4     < blk ? v.x : 0) + (b4 + 1 < blk ? v.y : 0)
          + (b4 + 2 < blk ? v.z : 0) + (b4 + 3 < blk ? v.w : 0);
    }
    tot[t] = s; myp[t] = sp;
  }
  __syncthreads();
  if (t == 0) {
    int run = 0;
    for (int b = 0; b < B; ++b) { start[b] = run; run += tot[b]; }
    start[B] = run;
  }
  __syncthreads();
  if (blk == 0 && t <= B) bs[t] = start[t];
  if (t < B) tot[t] = start[t] + myp[t];   // reuse tot[] as this block's cursors
  __syncthreads();
  int e0 = blk * chunk, e1 = min(ne, e0 + chunk);
  for (int i = e0 + t; i < e1; i += 256) {
    int c = col[i];
    int pos = atomicAdd(&tot[c >> 8], 1);
    tmp[pos] = (unsigned int)row[i] | ((unsigned int)(c & 255) << 16);
  }
}

// ---------------------------------------------------------------------------
// k3: per-bucket CSR finalize (blocks < B) OR gemm1 tiles from fp32 x
// (blocks >= B). ep written as ushort (N < 65536).
// ---------------------------------------------------------------------------
__global__ __launch_bounds__(256)
void csr_gemm1_kernel(const unsigned int* __restrict__ tmp, const int* __restrict__ bs,
                      int* __restrict__ rowp, float* __restrict__ dis,
                      float* __restrict__ dinv, unsigned short* __restrict__ ep,
                      int n, int B,
                      const float* __restrict__ X, const _Float16* __restrict__ W1t,
                      _Float16* __restrict__ Y) {
  int t = threadIdx.x, b = blockIdx.x;
  const int TG = gridDim.x;
  if (b < B) {
    __shared__ int h[256], lo[256], cur[256];
    h[t] = 0;
    __syncthreads();
    int s0 = bs[b], s1 = bs[b + 1];
    for (int i = s0 + t; i < s1; i += 256)
      atomicAdd(&h[(tmp[i] >> 16) & 255], 1);
    __syncthreads();
    if (t == 0) {
      int run = 0;
      for (int cb = 0; cb < 256; ++cb) { lo[cb] = run; run += h[cb]; }
    }
    __syncthreads();
    cur[t] = lo[t];
    int node = (b << 8) + t;
    if (node < n) {
      int c = h[t];
      rowp[node] = s0 + lo[t];
      float d = (float)(c + 1);   // +1 self loop
      dinv[node] = 1.0f / d;
      dis[node]  = rsqrtf(d);
      if (node == n - 1) rowp[n] = s1;   // last bucket end == E
    }
    __syncthreads();
    for (int i = s0 + t; i < s1; i += 256) {
      unsigned int v = tmp[i];
      int r = atomicAdd(&cur[(v >> 16) & 255], 1);
      ep[s0 + r] = (unsigned short)(v & 0xFFFFu);
    }
  } else {
    const int G2 = TG - B;   // 586 gemm blocks cover TG tiles
    for (int tile = b - B; tile < TG; tile += G2)
      gemm1_tile_f32(X, W1t, Y, n, tile, t);
  }
}

// ---------------------------------------------------------------------------
// k4: CH=128 aggregation, quarter scheme, 6 groups (24 edges) in flight,
// branch-free body, ushort ep. Writes packed epw[e] = src | half(w)<<16.
// ---------------------------------------------------------------------------
template<bool RELU>
__global__ __launch_bounds__(256)
void agg128h_kernel(const __half* __restrict__ xw, const int* __restrict__ row_ptr,
                    const unsigned short* __restrict__ ep, const float* __restrict__ dis,
                    unsigned int* __restrict__ epw, const float* __restrict__ deg_inv,
                    const float* __restrict__ bias, __half* __restrict__ out, int n) {
  int wave = (blockIdx.x * 256 + threadIdx.x) >> 6;
  int lane = threadIdx.x & 63;
  if (wave >= n) return;
  const int node = wave;
  const int s0 = row_ptr[node], s1 = row_ptr[node + 1];
  const int sub = lane & 15;
  const int q = lane >> 4;
  const float disc = dis[node];
  // prefetch epilogue operands (overlap with gather chains)
  float di = 0.f; float4 sraw = make_float4(0.f, 0.f, 0.f, 0.f);
  if (q == 0) {
    di = deg_inv[node];
    sraw = ((const float4*)(xw + (size_t)node * 128))[sub];
  }
  float acc[2][8];
#pragma unroll
  for (int g = 0; g < 2; ++g)
#pragma unroll
    for (int j = 0; j < 8; ++j) acc[g][j] = 0.f;
  for (int e = s0; e < s1; e += 24) {
    int eg[6], sg[6];
#pragma unroll
    for (int g = 0; g < 6; ++g) {
      eg[g] = e + 4 * g + q;
      int cg = min(eg[g], s1 - 1);
      sg[g] = (int)ep[cg];
    }
    float dg[6]; float4 raw[6];
#pragma unroll
    for (int g = 0; g < 6; ++g) {
      dg[g] = dis[sg[g]];
      raw[g] = ((const float4*)(xw + (size_t)sg[g] * 128))[sub];
    }
#pragma unroll
    for (int g = 0; g < 6; ++g) {
      bool ok = eg[g] < s1;
      if (sub == 0 && ok)
        epw[eg[g]] = (unsigned int)sg[g] |
                     ((unsigned int)__half_as_ushort(__float2half_rn(dg[g])) << 16);
      float wg = ok ? dg[g] * disc : 0.f;
      const __half2* hp = (const __half2*)&raw[g];
#pragma unroll
      for (int j = 0; j < 4; ++j) {
        float2 v = __half22float2(hp[j]);
        acc[g & 1][2 * j]     = fmaf(wg, v.x, acc[g & 1][2 * j]);
        acc[g & 1][2 * j + 1] = fmaf(wg, v.y, acc[g & 1][2 * j + 1]);
      }
    }
  }
#pragma unroll
  for (int j = 0; j < 8; ++j) {
    float s = acc[0][j] + acc[1][j];
    s += __shfl_xor(s, 16, 64);
    s += __shfl_xor(s, 32, 64);
    acc[0][j] = s;
  }
  if (q == 0) {
    const __half2* sp = (const __half2*)&sraw;
    const float4* bp = (const float4*)(bias + 8 * sub);
    float o[8];
#pragma unroll
    for (int j = 0; j < 4; ++j) {
      float2 sv = __half22float2(sp[j]);
      o[2 * j]     = acc[0][2 * j]     + sv.x * di;
      o[2 * j + 1] = acc[0][2 * j + 1] + sv.y * di;
    }
    float4 b0 = bp[0], b1v = bp[1];
    o[0] += b0.x; o[1] += b0.y; o[2] += b0.z; o[3] += b0.w;
    o[4] += b1v.x; o[5] += b1v.y; o[6] += b1v.z; o[7] += b1v.w;
    if (RELU) {
#pragma unroll
      for (int j = 0; j < 8; ++j) o[j] = fmaxf(o[j], 0.f);
    }
    __half2 h2[4];
#pragma unroll
    for (int j = 0; j < 4; ++j)
      h2[j] = __float22half2_rn(make_float2(o[2 * j], o[2 * j + 1]));
    *(float4*)(out + (size_t)node * 128 + 8 * sub) = *(const float4*)h2;
  }
}

// ---------------------------------------------------------------------------
// k6: CH=64 aggregation, OCT scheme, 4 groups (32 edges) in flight.
// One 4B packed {src:u16, w:fp16} load per edge.
// ---------------------------------------------------------------------------
template<bool RELU>
__global__ __launch_bounds__(256)
void agg64h_kernel(const __half* __restrict__ xw, const int* __restrict__ row_ptr,
                   const unsigned int* __restrict__ epw, const float* __restrict__ dis,
                   const float* __restrict__ deg_inv, const float* __restrict__ bias,
                   __half* __restrict__ out, int n) {
  int wave = (blockIdx.x * 256 + threadIdx.x) >> 6;
  int lane = threadIdx.x & 63;
  if (wave >= n) return;
  const int node = wave;
  const int s0 = row_ptr[node], s1 = row_ptr[node + 1];
  const int sub = lane & 7;       // 8 lanes x 16B = 128B row (8 ch each)
  const int oct = lane >> 3;      // 8 edges per group
  const float disc = dis[node];
  // prefetch epilogue operands
  float di = 0.f; float4 sraw = make_float4(0.f, 0.f, 0.f, 0.f);
  if (oct == 0) {
    di = deg_inv[node];
    sraw = ((const float4*)(xw + (size_t)node * 64))[sub];
  }
  float acc[2][8];
#pragma unroll
  for (int g = 0; g < 2; ++g)
#pragma unroll
    for (int j = 0; j < 8; ++j) acc[g][j] = 0.f;
  for (int e = s0; e < s1; e += 32) {
    int eg[4]; unsigned int pw[4];
#pragma unroll
    for (int g = 0; g < 4; ++g) {
      eg[g] = e + 8 * g + oct;
      int cg = min(eg[g], s1 - 1);
      pw[g] = epw[cg];
    }
    float4 raw[4];
#pragma unroll
    for (int g = 0; g < 4; ++g)
      raw[g] = ((const float4*)(xw + (size_t)(pw[g] & 0xFFFFu) * 64))[sub];
#pragma unroll
    for (int g = 0; g < 4; ++g) {
      float wsrc = __half2float(__ushort_as_half((unsigned short)(pw[g] >> 16)));
      float wg = (eg[g] < s1) ? wsrc * disc : 0.f;
      const __half2* hp = (const __half2*)&raw[g];
#pragma unroll
      for (int j = 0; j < 4; ++j) {
        float2 v = __half22float2(hp[j]);
        acc[g & 1][2 * j]     = fmaf(wg, v.x, acc[g & 1][2 * j]);
        acc[g & 1][2 * j + 1] = fmaf(wg, v.y, acc[g & 1][2 * j + 1]);
      }
    }
  }
#pragma unroll
  for (int j = 0; j < 8; ++j) {
    float s = acc[0][j] + acc[1][j];
    s += __shfl_xor(s, 8, 64);
    s += __shfl_xor(s, 16, 64);
    s += __shfl_xor(s, 32, 64);
    acc[0][j] = s;
  }
  if (oct == 0) {
    const __half2* sp = (const __half2*)&sraw;
    const float4* bp = (const float4*)(bias + 8 * sub);
    float o[8];
#pragma unroll
    for (int j = 0; j < 4; ++j) {
      float2 sv = __half22float2(sp[j]);
      o[2 * j]     = acc[0][2 * j]     + sv.x * di;
      o[2 * j + 1] = acc[0][2 * j + 1] + sv.y * di;
    }
    float4 b0 = bp[0], b1v = bp[1];
    o[0] += b0.x; o[1] += b0.y; o[2] += b0.z; o[3] += b0.w;
    o[4] += b1v.x; o[5] += b1v.y; o[6] += b1v.z; o[7] += b1v.w;
    if (RELU) {
#pragma unroll
      for (int j = 0; j < 8; ++j) o[j] = fmaxf(o[j], 0.f);
    }
    __half2 h2[4];
#pragma unroll
    for (int j = 0; j < 4; ++j)
      h2[j] = __float22half2_rn(make_float2(o[2 * j], o[2 * j + 1]));
    *(float4*)(out + (size_t)node * 64 + 8 * sub) = *(const float4*)h2;
  }
}

// k5: standalone gemm2 (fp16 input).
template<int M>
__global__ __launch_bounds__(256)
void gemm_mfma_kernel(const _Float16* __restrict__ Xh,
                      const _Float16* __restrict__ Wt,
                      _Float16* __restrict__ Y, int N) {
  gemm_tile<M>(Xh, Wt, Y, N, blockIdx.x, threadIdx.x);
}

// ---------------------------------------------------------------------------
// k7: decode — 12 pairs per wave, gathers batched before reductions (ILP 24).
// ---------------------------------------------------------------------------
__global__ __launch_bounds__(256)
void decode_kernel(const __half* __restrict__ z, const int* __restrict__ eli,
                   float* __restrict__ out, int nl) {
  int wave = (blockIdx.x * 256 + threadIdx.x) >> 6;
  int lane = threadIdx.x & 63;
  int p0 = wave * 12;
  if (p0 >= nl) return;
  int sub = lane & 31;
  float2 v[12];
#pragma unroll
  for (int j = 0; j < 12; ++j) {
    int p = min(p0 + j, nl - 1);
    int src = eli[p];
    int dst = eli[nl + p];
    int node = (lane < 32) ? src : dst;
    v[j] = __half22float2(((const __half2*)(z + (size_t)node * 64))[sub]);
  }
#pragma unroll
  for (int j = 0; j < 12; ++j) {
    int p = p0 + j;
    float ox = __shfl_xor(v[j].x, 32, 64);
    float oy = __shfl_xor(v[j].y, 32, 64);
    float pr = v[j].x * ox + v[j].y * oy;
#pragma unroll
    for (int m = 16; m >= 1; m >>= 1) pr += __shfl_xor(pr, m, 64);
    if (lane == 0 && p < nl) out[p] = pr;
  }
}

// ---------------------------------------------------------------------------

extern "C" void kernel_launch(void* const* d_in, const int* in_sizes, int n_in,
                              void* d_out, int out_size, void* d_ws, size_t ws_size,
                              hipStream_t stream) {
  const float* x  = (const float*)d_in[0];
  const float* W1 = (const float*)d_in[1];
  const float* b1 = (const float*)d_in[2];
  const float* W2 = (const float*)d_in[3];
  const float* b2 = (const float*)d_in[4];
  const int* eidx = (const int*)d_in[5];
  const int* eli  = (const int*)d_in[6];
  const int N  = in_sizes[0] / 128;
  const int E  = in_sizes[5] / 2;
  const int NL = in_sizes[6] / 2;
  float* out = (float*)d_out;

  char* ws = (char*)d_ws;
  size_t off = 0;
  auto alloc = [&](size_t bytes) -> char* {
    char* p = ws + off;
    off = (off + bytes + 255) & ~(size_t)255;
    return p;
  };
  const int B = (N + 255) / 256;        // buckets (col>>8); needs N <= 65536
  const int chunk = (E + NBLK - 1) / NBLK;
  float*          dis   = (float*)         alloc((size_t)N * 4);
  float*          dinv  = (float*)         alloc((size_t)N * 4);
  int*            rowp  = (int*)           alloc((size_t)(N + 1) * 4);
  int*            bhist = (int*)           alloc((size_t)NBLK * B * 4);
  int*            bs    = (int*)           alloc((size_t)(B + 1) * 4);
  unsigned int*   tmp   = (unsigned int*)  alloc((size_t)E * 4);
  unsigned short* ep    = (unsigned short*)alloc((size_t)E * 2);
  unsigned int*   epw   = (unsigned int*)  alloc((size_t)E * 4);
  _Float16*       W1t   = (_Float16*)      alloc((size_t)128 * 128 * 2);
  _Float16*       W2t   = (_Float16*)      alloc((size_t)64 * 128 * 2);
  __half*         bufA  = (__half*)        alloc((size_t)N * 128 * 2);
  __half*         bufB  = (__half*)        alloc((size_t)N * 128 * 2);
  __half*         bufC  = (__half*)        alloc((size_t)N * 64 * 2);
  __half*         z     = (__half*)        alloc((size_t)N * 64 * 2);
  (void)ws_size; (void)n_in; (void)out_size;

  const int* row = eidx;      // edge_index[0]
  const int* col = eidx + E;  // edge_index[1]
  const int TG = (N + 63) / 64;  // gemm tiles (782) > B (196)

  // k1: hist (bucket-major) + W transposes
  hist_prep_kernel<<<NBLK, 256, 0, stream>>>(W1, W2, W1t, W2t, col, bhist,
                                             E, chunk, B);
  // k2: scatter with fused base computation (vectorized prefix, packed tmp)
  scatter_base_kernel<<<NBLK, 256, 0, stream>>>(row, col, bhist, tmp, bs, E, chunk, B);
  // k3: CSR finalize (blocks < B) | gemm1 tiles from fp32 x (blocks >= B)
  csr_gemm1_kernel<<<TG, 256, 0, stream>>>(tmp, bs, rowp, dis, dinv, ep, N, B,
                                           x, W1t, (_Float16*)bufA);
  // k4: bufB = half(relu(agg(bufA)+dinv*bufA+b1)); writes packed epw[]
  agg128h_kernel<true><<<(N + 3) / 4, 256, 0, stream>>>(bufA, rowp, ep, dis, epw,
                                                        dinv, b1, bufB, N);
  // k5: bufC = half(bufB@W2)
  gemm_mfma_kernel<64><<<TG, 256, 0, stream>>>((const _Float16*)bufB, W2t,
                                               (_Float16*)bufC, N);
  // k6: z = half(agg(bufC)+dinv*bufC+b2) using packed epw[]
  agg64h_kernel<false><<<(N + 3) / 4, 256, 0, stream>>>(bufC, rowp, epw, dis,
                                                        dinv, b2, z, N);
  // k7: decode (12 pairs/wave)
  decode_kernel<<<(NL + 47) / 48, 256, 0, stream>>>(z, eli, out, NL);
}